// Round 17
// baseline (240.119 us; speedup 1.0000x reference)
//
#include <hip/hip_runtime.h>
#include <hip/hip_bf16.h>
#include <math.h>

#define NB 16
#define NLAT 512
#define NCTX 1024
#define CD 512
#define NH 8
#define HD 64

typedef unsigned short ushort_t;
typedef __attribute__((ext_vector_type(8))) __bf16 bf16x8;
typedef __attribute__((ext_vector_type(8))) unsigned short u16x8;
typedef __attribute__((ext_vector_type(4))) unsigned short u16x4;
typedef __attribute__((ext_vector_type(4))) float f32x4;
typedef __attribute__((ext_vector_type(2))) unsigned int u32x2;

__device__ __forceinline__ float bf2f(unsigned short u) {
  return __uint_as_float(((unsigned int)u) << 16);
}
__device__ __forceinline__ unsigned short f2bf(float f) {
  unsigned int x = __float_as_uint(f);
  return (unsigned short)((x + 0x7fffu + ((x >> 16) & 1u)) >> 16);
}
__device__ __forceinline__ float gelu_f(float x) {
  return 0.5f * x * (1.f + erff(x * 0.70710678118654752f));
}

typedef const __attribute__((address_space(1))) unsigned int* gptr1;
typedef __attribute__((address_space(3))) unsigned int* lptr3;
__device__ __forceinline__ void gload16(const void* g, void* l) {
  __builtin_amdgcn_global_load_lds((gptr1)g, (lptr3)l, 16, 0, 0);
}
__device__ __forceinline__ u32x2 tr64(unsigned a) {
  u32x2 d;
  asm volatile("ds_read_b64_tr_b16 %0, %1" : "=v"(d) : "v"(a));
  return d;
}
__device__ __forceinline__ void gload16_s(const void* g, unsigned sbase) {
  asm volatile("s_mov_b32 m0, %0\n"
               "global_load_lds_dwordx4 %1, off"
               :: "s"(sbase), "v"(g) : "memory");
}
__device__ __forceinline__ void gload16_asm(const void* g, unsigned lds_uniform_base) {
  unsigned sb = __builtin_amdgcn_readfirstlane(lds_uniform_base);
  asm volatile("s_mov_b32 m0, %0\n"
               "global_load_lds_dwordx4 %1, off"
               :: "s"(sb), "v"(g) : "memory");
}
template<int N> __device__ __forceinline__ void vmwait() {
  if constexpr (N == 0)       asm volatile("s_waitcnt vmcnt(0)" ::: "memory");
  else if constexpr (N == 2)  asm volatile("s_waitcnt vmcnt(2)" ::: "memory");
  else if constexpr (N == 3)  asm volatile("s_waitcnt vmcnt(3)" ::: "memory");
  else if constexpr (N == 4)  asm volatile("s_waitcnt vmcnt(4)" ::: "memory");
  else if constexpr (N == 6)  asm volatile("s_waitcnt vmcnt(6)" ::: "memory");
  else if constexpr (N == 8)  asm volatile("s_waitcnt vmcnt(8)" ::: "memory");
}

// ---------------- LN row helper (one wave per row of 512)
__device__ __forceinline__ void ln_row(const float* __restrict__ x,
                                       const float* __restrict__ gw,
                                       const float* __restrict__ gb,
                                       ushort_t* __restrict__ out,
                                       int row, int lane) {
  const float4* xr = (const float4*)(x + (size_t)row * CD);
  float4 a = xr[lane * 2], b = xr[lane * 2 + 1];
  float s  = a.x + a.y + a.z + a.w + b.x + b.y + b.z + b.w;
  float s2 = a.x*a.x + a.y*a.y + a.z*a.z + a.w*a.w + b.x*b.x + b.y*b.y + b.z*b.z + b.w*b.w;
  for (int off = 32; off; off >>= 1) { s += __shfl_xor(s, off); s2 += __shfl_xor(s2, off); }
  float mean = s * (1.f / CD);
  float inv = rsqrtf(s2 * (1.f / CD) - mean * mean + 1e-5f);
  const float4* wv = (const float4*)gw;
  const float4* bv = (const float4*)gb;
  float4 w0 = wv[lane*2], w1 = wv[lane*2+1], c0 = bv[lane*2], c1 = bv[lane*2+1];
  u16x8 o;
  o[0] = f2bf((a.x - mean) * inv * w0.x + c0.x);
  o[1] = f2bf((a.y - mean) * inv * w0.y + c0.y);
  o[2] = f2bf((a.z - mean) * inv * w0.z + c0.z);
  o[3] = f2bf((a.w - mean) * inv * w0.w + c0.w);
  o[4] = f2bf((b.x - mean) * inv * w1.x + c1.x);
  o[5] = f2bf((b.y - mean) * inv * w1.y + c1.y);
  o[6] = f2bf((b.z - mean) * inv * w1.z + c1.z);
  o[7] = f2bf((b.w - mean) * inv * w1.w + c1.w);
  *(u16x8*)(out + (size_t)row * CD + lane * 8) = o;
}

// ---------------- merged prep: 7 weight transposes + bias_cat + both LayerNorms
__global__ __launch_bounds__(256)
void prep_all(const float* __restrict__ Wq, const float* __restrict__ Wk,
              const float* __restrict__ Wf, const float* __restrict__ hw_,
              const float* __restrict__ Wp, const float* __restrict__ f1,
              const float* __restrict__ f2, const float* __restrict__ bfv,
              ushort_t* __restrict__ WqT, ushort_t* __restrict__ WkT,
              ushort_t* __restrict__ WfT, ushort_t* __restrict__ hwT,
              ushort_t* __restrict__ WpT, ushort_t* __restrict__ fc1T,
              ushort_t* __restrict__ fc2T, float* __restrict__ biaskf,
              const float* __restrict__ latents, const float* __restrict__ nlw,
              const float* __restrict__ nlb, ushort_t* __restrict__ xl,
              const float* __restrict__ context, const float* __restrict__ ncw,
              const float* __restrict__ ncb, ushort_t* __restrict__ xc) {
  int b = blockIdx.x;
  if (b >= 3345) {   // LayerNorm section
    int lb = b - 3345;
    int lane = threadIdx.x & 63, wvi = threadIdx.x >> 6;
    if (lb < 2048) ln_row(latents, nlw, nlb, xl, lb * 4 + wvi, lane);
    else           ln_row(context, ncw, ncb, xc, (lb - 2048) * 4 + wvi, lane);
    return;
  }
  if (b == 3344) {   // bias_cat tail
    int i = threadIdx.x;
#pragma unroll
    for (int j = 0; j < 4; j++) {
      int idx = j * 256 + i;
      biaskf[idx] = (idx < 512) ? 0.f : bfv[idx - 512];
    }
    return;
  }
  const float* W; ushort_t* WT; int K, N, tile;
  if (b < 256)       { W = Wq;  WT = WqT;  K = 512;  N = 512;  tile = b; }
  else if (b < 512)  { W = Wk;  WT = WkT;  K = 512;  N = 512;  tile = b - 256; }
  else if (b < 784)  { W = Wf;  WT = WfT;  K = 512;  N = 515;  tile = b - 512; }
  else if (b < 1040) { W = hw_; WT = hwT;  K = 512;  N = 512;  tile = b - 784; }
  else if (b < 1296) { W = Wp;  WT = WpT;  K = 512;  N = 512;  tile = b - 1040; }
  else if (b < 2320) { W = f1;  WT = fc1T; K = 512;  N = 2048; tile = b - 1296; }
  else               { W = f2;  WT = fc2T; K = 2048; N = 512;  tile = b - 2320; }
  int Kt = K >> 5;
  int kb = (tile % Kt) * 32, nb = (tile / Kt) * 32;
  __shared__ float ts[32][33];
  int tx = threadIdx.x & 31, ty = threadIdx.x >> 5;
  for (int i = ty; i < 32; i += 8) {
    int k = kb + i, n = nb + tx;
    ts[i][tx] = (k < K && n < N) ? W[(size_t)k * N + n] : 0.f;
  }
  __syncthreads();
  for (int i = ty; i < 32; i += 8) {
    int n = nb + i, k = kb + tx;
    if (n < N && k < K) WT[(size_t)n * K + k] = f2bf(ts[tx][i]);
  }
}

// ---------------- standalone LN (for post-proj lat1 -> h2)
__global__ __launch_bounds__(256)
void ln_kernel(const float* __restrict__ x, const float* __restrict__ gw,
               const float* __restrict__ gb, ushort_t* __restrict__ out, int nrows) {
  ln_row(x, gw, gb, out, blockIdx.x * 4 + (threadIdx.x >> 6), threadIdx.x & 63);
  (void)nrows;
}

// ---------------- gemm10 (r14-exact): 128x64 block, BK=32, 4-slot ring,
// two slots per barrier pair, full-bank swizzle seg' = seg ^ ((row>>1)&3).
template<int BM, int BN, int ACT_GELU, int HAS_BIAS, int HAS_RES, int OUT_BF16>
__global__ __launch_bounds__(256)
void gemm10(const ushort_t* __restrict__ A, const ushort_t* __restrict__ BT,
            const float* __restrict__ bias, const float* __restrict__ res,
            void* __restrict__ outp, int N, int K) {
  constexpr int TM = BM / 2, FM = TM / 16;
  constexpr int TN = BN / 2, FN = TN / 16;
  constexpr int LA = BM / 64, LB = BN / 64, L = LA + LB;
  constexpr int SLOT = (BM + BN) * 32;
  __shared__ __attribute__((aligned(16))) ushort_t SH[4][SLOT];

  const int t = threadIdx.x;
  const int lane = t & 63;
  const int wv = t >> 6;
  const int wr = wv >> 1, wc = wv & 1;
  const int g = lane >> 4, l15 = lane & 15;
  const int xsw = (g ^ ((l15 >> 1) & 3)) * 8;
  const size_t m0 = (size_t)blockIdx.x * BM;
  const size_t n0 = (size_t)blockIdx.y * BN;
  const int nK = K >> 5;

  f32x4 acc[FM][FN] = {};

  const ushort_t* Abase = A + m0 * K;
  const ushort_t* Bbase = BT + n0 * K;
  const unsigned shb = (unsigned)(size_t)(lptr3)&SH[0][0];
  const unsigned wofs = (unsigned)wv * 1024;

  auto stage = [&](int s, int kt) {
    const unsigned sb = shb + (unsigned)s * (SLOT * 2);
    const ushort_t* As = Abase + (size_t)kt * 32;
#pragma unroll
    for (int i = 0; i < LA; i++) {
      int li = i * 256 + t;
      int sc = ((li & 3) ^ ((li >> 3) & 3)) * 8;
      gload16_asm(As + (size_t)(li >> 2) * K + sc, sb + (unsigned)i * 4096 + wofs);
    }
    const ushort_t* Bs = Bbase + (size_t)kt * 32;
#pragma unroll
    for (int i = 0; i < LB; i++) {
      int li = i * 256 + t;
      int sc = ((li & 3) ^ ((li >> 3) & 3)) * 8;
      gload16_asm(Bs + (size_t)(li >> 2) * K + sc, sb + (unsigned)(BM * 64) + (unsigned)i * 4096 + wofs);
    }
  };

  auto compute = [&](int s) {
    const ushort_t* base = &SH[0][0] + s * SLOT;
    const ushort_t* Ab = base + wr * TM * 32;
    const ushort_t* Bb = base + BM * 32 + wc * TN * 32;
    bf16x8 Bf[FN], Af[FM];
#pragma unroll
    for (int n = 0; n < FN; n++)
      Bf[n] = *(const bf16x8*)(Bb + (n * 16 + l15) * 32 + xsw);
#pragma unroll
    for (int m = 0; m < FM; m++)
      Af[m] = *(const bf16x8*)(Ab + (m * 16 + l15) * 32 + xsw);
    __builtin_amdgcn_s_setprio(1);
#pragma unroll
    for (int m = 0; m < FM; m++)
#pragma unroll
      for (int n = 0; n < FN; n++)
        acc[m][n] = __builtin_amdgcn_mfma_f32_16x16x32_bf16(Af[m], Bf[n], acc[m][n], 0, 0, 0);
    __builtin_amdgcn_s_setprio(0);
  };

  stage(0, 0); stage(1, 1);
  for (int kt = 0; kt < nK; kt += 2) {
    if (kt + 2 < nK) {
      stage((kt + 2) & 3, kt + 2);
      stage((kt + 3) & 3, kt + 3);
      vmwait<2 * L>();
    } else {
      vmwait<0>();
    }
    __builtin_amdgcn_s_barrier();
    __builtin_amdgcn_sched_barrier(0);
    compute(kt & 3);
    compute((kt + 1) & 3);
    __builtin_amdgcn_sched_barrier(0);
    __builtin_amdgcn_s_barrier();
  }

  const int colb = (int)n0 + wc * TN;
  float bv[FN];
#pragma unroll
  for (int n = 0; n < FN; n++) bv[n] = HAS_BIAS ? bias[colb + n * 16 + l15] : 0.f;

  if (OUT_BF16) {
    constexpr int ES = TN + 8;
    ushort_t* ep = &SH[0][0] + wv * (TM * ES);
#pragma unroll
    for (int m = 0; m < FM; m++)
#pragma unroll
      for (int n = 0; n < FN; n++)
#pragma unroll
        for (int r = 0; r < 4; r++) {
          float v = acc[m][n][r] + bv[n];
          if (ACT_GELU) v = gelu_f(v);
          ep[(m * 16 + g * 4 + r) * ES + n * 16 + l15] = f2bf(v);
        }
    asm volatile("s_waitcnt lgkmcnt(0)" ::: "memory");
    __builtin_amdgcn_sched_barrier(0);
    const size_t gr0 = m0 + wr * TM;
#pragma unroll
    for (int c = 0; c < TM * TN / 512; c++) {
      int idx = c * 512 + lane * 8;
      int lr = idx / TN, col = idx % TN;
      u16x8 vvv = *(const u16x8*)&ep[lr * ES + col];
      *(u16x8*)((ushort_t*)outp + (gr0 + lr) * N + colb + col) = vvv;
    }
  } else {
    const int rowb = (int)m0 + wr * TM + g * 4;
#pragma unroll
    for (int n = 0; n < FN; n++) {
      int col = colb + n * 16 + l15;
#pragma unroll
      for (int m = 0; m < FM; m++) {
#pragma unroll
        for (int r = 0; r < 4; r++) {
          size_t idx = (size_t)(rowb + m * 16 + r) * N + col;
          float v = acc[m][n][r] + bv[n];
          if (ACT_GELU) v = gelu_f(v);
          if (HAS_RES) v += res[idx];
          ((float*)outp)[idx] = v;
        }
      }
    }
  }
}

// ---------------- gemm11 (r15-exact): 64x64 tile, 3-slot 24KB ring (6 blocks/CU),
// XCD-chunked decode, full-bank swizzle. For the two 17.2-GF shapes (kf, fc1).
template<int ACT_GELU, int HAS_BIAS, int HAS_RES, int OUT_BF16>
__global__ __launch_bounds__(256)
void gemm11(const ushort_t* __restrict__ A, const ushort_t* __restrict__ BT,
            const float* __restrict__ bias, const float* __restrict__ res,
            void* __restrict__ outp, int N, int K, int nN) {
  constexpr int SLOT = 4096;
  __shared__ __attribute__((aligned(16))) ushort_t SH[3][SLOT];

  const int bid = blockIdx.x;
  const int q = gridDim.x >> 3;
  const int lin = (bid & 7) * q + (bid >> 3);
  const size_t m0 = (size_t)(lin / nN) * 64;
  const size_t n0 = (size_t)(lin % nN) * 64;

  const int t = threadIdx.x;
  const int lane = t & 63;
  const int wv = t >> 6;
  const int wr = wv >> 1, wc = wv & 1;
  const int g = lane >> 4, l15 = lane & 15;
  const int xsw = (g ^ ((l15 >> 1) & 3)) * 8;
  const int nK = K >> 5;

  f32x4 acc[2][2] = {};

  const ushort_t* Abase = A + m0 * K;
  const ushort_t* Bbase = BT + n0 * K;
  const unsigned m0b = __builtin_amdgcn_readfirstlane(
      (unsigned)(size_t)(lptr3)&SH[0][0] + (unsigned)wv * 1024u);

  const int srow = t >> 2;
  const int ssc = ((t & 3) ^ ((t >> 3) & 3)) * 8;

  auto stage = [&](int s, int kt) {
    const unsigned sb = m0b + (unsigned)s * 8192u;
    gload16_s(Abase + (size_t)srow * K + (size_t)kt * 32 + ssc, sb);
    gload16_s(Bbase + (size_t)srow * K + (size_t)kt * 32 + ssc, sb + 4096u);
  };

  auto compute = [&](int s) {
    const ushort_t* base = &SH[0][0] + s * SLOT;
    const ushort_t* Ab = base + wr * (32 * 32);
    const ushort_t* Bb = base + 64 * 32 + wc * (32 * 32);
    bf16x8 Bf[2], Af[2];
#pragma unroll
    for (int n = 0; n < 2; n++)
      Bf[n] = *(const bf16x8*)(Bb + (n * 16 + l15) * 32 + xsw);
#pragma unroll
    for (int m = 0; m < 2; m++)
      Af[m] = *(const bf16x8*)(Ab + (m * 16 + l15) * 32 + xsw);
    __builtin_amdgcn_s_setprio(1);
#pragma unroll
    for (int m = 0; m < 2; m++)
#pragma unroll
      for (int n = 0; n < 2; n++)
        acc[m][n] = __builtin_amdgcn_mfma_f32_16x16x32_bf16(Af[m], Bf[n], acc[m][n], 0, 0, 0);
    __builtin_amdgcn_s_setprio(0);
  };

  stage(0, 0); stage(1, 1);
  for (int kt = 0; kt < nK; kt++) {
    int s = kt % 3;
    if (kt + 2 < nK) { stage((kt + 2) % 3, kt + 2); vmwait<4>(); }
    else if (kt + 1 < nK) vmwait<2>();
    else vmwait<0>();
    __builtin_amdgcn_s_barrier();
    __builtin_amdgcn_sched_barrier(0);
    compute(s);
    __builtin_amdgcn_sched_barrier(0);
    __builtin_amdgcn_s_barrier();
  }

  const int colb = (int)n0 + wc * 32;
  float bv[2];
#pragma unroll
  for (int n = 0; n < 2; n++) bv[n] = HAS_BIAS ? bias[colb + n * 16 + l15] : 0.f;

  if (OUT_BF16) {
    constexpr int ES = 40;
    ushort_t* ep = &SH[0][0] + wv * (32 * ES);
#pragma unroll
    for (int m = 0; m < 2; m++)
#pragma unroll
      for (int n = 0; n < 2; n++)
#pragma unroll
        for (int r = 0; r < 4; r++) {
          float v = acc[m][n][r] + bv[n];
          if (ACT_GELU) v = gelu_f(v);
          ep[(m * 16 + g * 4 + r) * ES + n * 16 + l15] = f2bf(v);
        }
    asm volatile("s_waitcnt lgkmcnt(0)" ::: "memory");
    __builtin_amdgcn_sched_barrier(0);
    const size_t gr0 = m0 + wr * 32;
#pragma unroll
    for (int c = 0; c < 2; c++) {
      int idx = c * 512 + lane * 8;
      int lr = idx >> 5, col = idx & 31;
      u16x8 vvv = *(const u16x8*)&ep[lr * ES + col];
      *(u16x8*)((ushort_t*)outp + (gr0 + lr) * N + colb + col) = vvv;
    }
  } else {
    const int rowb = (int)m0 + wr * 32 + g * 4;
#pragma unroll
    for (int n = 0; n < 2; n++) {
      int col = colb + n * 16 + l15;
#pragma unroll
      for (int m = 0; m < 2; m++) {
#pragma unroll
        for (int r = 0; r < 4; r++) {
          size_t idx = (size_t)(rowb + m * 16 + r) * N + col;
          float v = acc[m][n][r] + bv[n];
          if (ACT_GELU) v = gelu_f(v);
          if (HAS_RES) v += res[idx];
          ((float*)outp)[idx] = v;
        }
      }
    }
  }
}

// ---------------- gates: 3 matvec outputs per context row -> (B,3,HW) f32
__global__ __launch_bounds__(256)
void gates_kernel(const ushort_t* __restrict__ xc, const ushort_t* __restrict__ WfT,
                  const float* __restrict__ bfv, float* __restrict__ gates) {
  int row = blockIdx.x * 4 + (threadIdx.x >> 6);
  int lane = threadIdx.x & 63;
  u16x8 xv = *(const u16x8*)(xc + (size_t)row * CD + lane * 8);
  float xf[8];
#pragma unroll
  for (int e = 0; e < 8; e++) xf[e] = bf2f(xv[e]);
  float sl[3];
#pragma unroll
  for (int l = 0; l < 3; l++) {
    u16x8 wvv = *(const u16x8*)(WfT + (size_t)(CD + l) * CD + lane * 8);
    float d = 0.f;
#pragma unroll
    for (int e = 0; e < 8; e++) d += xf[e] * bf2f(wvv[e]);
    for (int off = 32; off; off >>= 1) d += __shfl_xor(d, off);
    sl[l] = d;
  }
  if (lane == 0) {
    int b = row >> 10, p = row & 1023;
#pragma unroll
    for (int l = 0; l < 3; l++) gates[((size_t)b * 3 + l) * 1024 + p] = sl[l] + bfv[CD + l];
  }
}

// ---------------- bf16 transpose per batch: out[b][c][r] = in[b*ibs + r*irs + c]
__global__ __launch_bounds__(256)
void tr_bf16(const ushort_t* __restrict__ in, ushort_t* __restrict__ out, int R, int C,
             int irs, size_t ibs, size_t obs) {
  __shared__ ushort_t tile[64][72];
  size_t ibase = (size_t)blockIdx.z * ibs;
  size_t obase = (size_t)blockIdx.z * obs;
  int r0 = blockIdx.x * 64, c0 = blockIdx.y * 64;
  int t = threadIdx.x;
#pragma unroll
  for (int j = 0; j < 2; j++) {
    int lin = j * 256 + t;
    int r = lin >> 3, cc = (lin & 7) * 8;
    u16x8 v = *(const u16x8*)(in + ibase + (size_t)(r0 + r) * irs + c0 + cc);
#pragma unroll
    for (int e = 0; e < 8; e++) tile[r][cc + e] = v[e];
  }
  __syncthreads();
#pragma unroll
  for (int j = 0; j < 2; j++) {
    int lin = j * 256 + t;
    int c = lin >> 3, rr = (lin & 7) * 8;
    u16x8 v;
#pragma unroll
    for (int e = 0; e < 8; e++) v[e] = tile[rr + e][c];
    *(u16x8*)(out + obase + (size_t)(c0 + c) * R + r0 + rr) = v;
  }
}

// ---------------- focal conv v2: zero-padded LDS halos, branch-free FMA chains.
__global__ __launch_bounds__(256)
void focal_conv(const ushort_t* __restrict__ ft, const float* __restrict__ gates,
                const float* __restrict__ fk0, const float* __restrict__ fk1,
                ushort_t* __restrict__ accc) {
  int bc = blockIdx.x;
  int b = bc >> 9, c = bc & 511;
  __shared__ float xs[34][37];
  __shared__ float vs[38][41];
  __shared__ float w0s[9], w1s[25];
  __shared__ float red[4];
  const int t = threadIdx.x;
  const int hh = t >> 3;
  const int w0c = (t & 7) * 4;

  float* xz = &xs[0][0];
  float* vz = &vs[0][0];
#pragma unroll
  for (int i = 0; i < 5; i++) { int idx = t + i * 256; if (idx < 34 * 37) xz[idx] = 0.f; }
#pragma unroll
  for (int i = 0; i < 7; i++) { int idx = t + i * 256; if (idx < 38 * 41) vz[idx] = 0.f; }
  if (t < 9)  w0s[t] = fk0[c * 9 + t];
  if (t < 25) w1s[t] = fk1[c * 25 + t];

  u16x4 vin = *(const u16x4*)(ft + (size_t)bc * 1024 + t * 4);
  const float* g0 = gates + (size_t)b * 3 * 1024;
  float4 ga = *(const float4*)(g0 + t * 4);
  float4 gb = *(const float4*)(g0 + 1024 + t * 4);
  float4 gc = *(const float4*)(g0 + 2048 + t * 4);
  __syncthreads();
#pragma unroll
  for (int j = 0; j < 4; j++) xs[hh + 1][w0c + 1 + j] = bf2f(vin[j]);
  __syncthreads();

  float accv[4];
  const float* gav = (const float*)&ga;
  const float* gbv = (const float*)&gb;
  const float* gcv = (const float*)&gc;
#pragma unroll
  for (int j = 0; j < 4; j++) {
    int ww = w0c + j;
    float s = 0.f;
#pragma unroll
    for (int dh = 0; dh < 3; dh++)
#pragma unroll
      for (int dw = 0; dw < 3; dw++)
        s += xs[hh + dh][ww + dw] * w0s[dh * 3 + dw];
    float v1 = gelu_f(s);
    vs[hh + 2][ww + 2] = v1;
    accv[j] = v1 * gav[j];
  }
  __syncthreads();

  float psum = 0.f;
#pragma unroll
  for (int j = 0; j < 4; j++) {
    int ww = w0c + j;
    float s = 0.f;
#pragma unroll
    for (int dh = 0; dh < 5; dh++)
#pragma unroll
      for (int dw = 0; dw < 5; dw++)
        s += vs[hh + dh][ww + dw] * w1s[dh * 5 + dw];
    float v2 = gelu_f(s);
    psum += v2;
    accv[j] += v2 * gbv[j];
  }
  for (int off = 32; off; off >>= 1) psum += __shfl_xor(psum, off);
  if ((t & 63) == 0) red[t >> 6] = psum;
  __syncthreads();
  float g = gelu_f((red[0] + red[1] + red[2] + red[3]) * (1.f / 1024.f));
  u16x4 o;
#pragma unroll
  for (int j = 0; j < 4; j++) o[j] = f2bf(accv[j] + g * gcv[j]);
  *(u16x4*)(accc + (size_t)bc * 1024 + t * 4) = o;
}

// ---------------- flash attention v3: no-max softmax, deferred denominator,
// batched tr64, XCD swizzle.
__global__ __launch_bounds__(512)
void flash_attn(const ushort_t* __restrict__ Q, const ushort_t* __restrict__ Kk,
                const ushort_t* __restrict__ V, ushort_t* __restrict__ Y, int kstride) {
  const int wg = blockIdx.x;
  const int swz = (wg & 7) * 64 + (wg >> 3);
  const int q0 = (swz & 3) * 128;
  const int h = (swz >> 2) & 7;
  const int b = swz >> 5;
  const int t = threadIdx.x, lane = t & 63, w = t >> 6;
  const int g = lane >> 4, l15 = lane & 15;
  __shared__ __attribute__((aligned(16))) ushort_t Ks[2][4096];
  __shared__ __attribute__((aligned(16))) ushort_t Vs[2][4096];
  __shared__ __attribute__((aligned(16))) ushort_t Ps[8][1024];

  const size_t qbase = (((size_t)b * NLAT) + q0 + w * 16 + l15) * CD + h * HD;
  bf16x8 aq[2];
#pragma unroll
  for (int kk = 0; kk < 2; kk++) {
    u16x8 u = *(const u16x8*)(Q + qbase + kk * 32 + g * 8);
    u16x8 o;
#pragma unroll
    for (int e = 0; e < 8; e++) o[e] = f2bf(bf2f(u[e]) * 0.125f);
    aq[kk] = *(bf16x8*)&o;
  }

  f32x4 accO[4] = {};
  float lsum[4] = {0.f, 0.f, 0.f, 0.f};
  const ushort_t* Kb = Kk + ((size_t)b * NCTX) * kstride + h * HD;
  const ushort_t* Vb = V  + ((size_t)b * NCTX) * CD + h * HD;
  const int krow = t >> 3;
  const int kseg = 8 * ((t & 7) ^ (krow & 7));
  const int vrow = (t >> 1) & 63;
  const int vcol = (t >> 7) * 16 + (t & 1) * 8;

  auto stage = [&](int buf, int kv) {
    const int k0 = kv * 64;
    gload16(Kb + (size_t)(k0 + krow) * kstride + kseg, &Ks[buf][t * 8]);
    gload16(Vb + (size_t)(k0 + vrow) * CD + vcol, &Vs[buf][t * 8]);
  };

  const unsigned vsbase0 = (unsigned)(size_t)(lptr3)&Vs[0][0];
  const unsigned vsbase1 = (unsigned)(size_t)(lptr3)&Vs[1][0];
  char* psb = (char*)&Ps[w][0];

  stage(0, 0);
  __syncthreads();
  int cur = 0;
  for (int kv = 0; kv < 16; kv++) {
    if (kv < 15) stage(cur ^ 1, kv + 1);

    const char* ksb = (const char*)&Ks[cur][0];
    f32x4 accS[4] = {};
#pragma unroll
    for (int kk = 0; kk < 2; kk++) {
#pragma unroll
      for (int n = 0; n < 4; n++) {
        int rr = n * 16 + l15;
        bf16x8 bk = *(const bf16x8*)(ksb + rr * 128 + ((kk * 64 + g * 16) ^ ((rr & 7) << 4)));
        accS[n] = __builtin_amdgcn_mfma_f32_16x16x32_bf16(aq[kk], bk, accS[n], 0, 0, 0);
      }
    }

#pragma unroll
    for (int n = 0; n < 4; n++)
#pragma unroll
      for (int r = 0; r < 4; r++) {
        float p = __expf(accS[n][r]);
        accS[n][r] = p;
        lsum[r] += p;
      }

#pragma unroll
    for (int n = 0; n < 4; n++)
#pragma unroll
      for (int r = 0; r < 4; r++) {
        int row = g * 4 + r;
        int cb = (n * 16 + l15) * 2;
        *(ushort_t*)(psb + row * 128 + (cb ^ ((row & 7) << 4))) = f2bf(accS[n][r]);
      }
    asm volatile("s_waitcnt lgkmcnt(0)" ::: "memory");
    __builtin_amdgcn_sched_barrier(0);
    bf16x8 ap0 = *(const bf16x8*)(psb + l15 * 128 + (((g * 16)) ^ ((l15 & 7) << 4)));
    bf16x8 ap1 = *(const bf16x8*)(psb + l15 * 128 + ((64 + g * 16) ^ ((l15 & 7) << 4)));

    const unsigned vsb = (cur ? vsbase1 : vsbase0) + g * 128;
    union PKU { u32x2 d2[2]; bf16x8 v; };
    PKU pk[8];
#pragma unroll
    for (int n = 0; n < 4; n++) {
      unsigned a = vsb + n * 2048;
      pk[n * 2].d2[0]     = tr64(a);
      pk[n * 2].d2[1]     = tr64(a + 128);
      pk[n * 2 + 1].d2[0] = tr64(a + 1024);
      pk[n * 2 + 1].d2[1] = tr64(a + 1152);
    }
    asm volatile("s_waitcnt lgkmcnt(0)" ::: "memory");
    __builtin_amdgcn_sched_barrier(0);
#pragma unroll
    for (int n = 0; n < 4; n++) {
      accO[n] = __builtin_amdgcn_mfma_f32_16x16x32_bf16(ap0, pk[n * 2].v, accO[n], 0, 0, 0);
      accO[n] = __builtin_amdgcn_mfma_f32_16x16x32_bf16(ap1, pk[n * 2 + 1].v, accO[n], 0, 0, 0);
    }
    __syncthreads();
    cur ^= 1;
  }

#pragma unroll
  for (int r = 0; r < 4; r++) {
    float s = lsum[r];
    s += __shfl_xor(s, 1); s += __shfl_xor(s, 2);
    s += __shfl_xor(s, 4); s += __shfl_xor(s, 8);
    lsum[r] = 1.f / s;
  }
#pragma unroll
  for (int n = 0; n < 4; n++) {
#pragma unroll
    for (int r = 0; r < 4; r++) {
      size_t row = q0 + w * 16 + g * 4 + r;
      size_t col = h * HD + n * 16 + l15;
      Y[(((size_t)b * NLAT) + row) * CD + col] = f2bf(accO[n][r] * lsum[r]);
    }
  }
}

// ---------------- host orchestration
extern "C" void kernel_launch(void* const* d_in, const int* in_sizes, int n_in,
                              void* d_out, int out_size, void* d_ws, size_t ws_size,
                              hipStream_t stream) {
  const float* latents  = (const float*)d_in[0];
  const float* context  = (const float*)d_in[1];
  const float* norm_l_w = (const float*)d_in[4];
  const float* norm_l_b = (const float*)d_in[5];
  const float* norm_c_w = (const float*)d_in[6];
  const float* norm_c_b = (const float*)d_in[7];
  const float* norm2_w  = (const float*)d_in[8];
  const float* norm2_b  = (const float*)d_in[9];
  const float* Wq    = (const float*)d_in[10];
  const float* Wk    = (const float*)d_in[11];
  const float* Wf    = (const float*)d_in[12];
  const float* bfv   = (const float*)d_in[13];
  const float* fk0   = (const float*)d_in[14];
  const float* fk1   = (const float*)d_in[15];
  const float* h_w   = (const float*)d_in[16];
  const float* h_b   = (const float*)d_in[17];
  const float* Wproj = (const float*)d_in[18];
  const float* bproj = (const float*)d_in[19];
  const float* fc1_w = (const float*)d_in[20];
  const float* fc1_b = (const float*)d_in[21];
  const float* fc2_w = (const float*)d_in[22];
  const float* fc2_b = (const float*)d_in[23];

  char* ws = (char*)d_ws;
  const size_t MB = 1024ull * 1024ull;
  ushort_t* WqT  = (ushort_t*)(ws + 0 * MB);
  ushort_t* WkT  = (ushort_t*)(ws + 1 * MB);
  ushort_t* WfT  = (ushort_t*)(ws + 1 * MB + 524288);
  ushort_t* hwT  = (ushort_t*)(ws + 3 * MB);
  ushort_t* WpT  = (ushort_t*)(ws + 4 * MB);
  ushort_t* fc1T = (ushort_t*)(ws + 5 * MB);
  ushort_t* fc2T = (ushort_t*)(ws + 7 * MB);
  float*    biaskf = (float*)(ws + 9 * MB);
  ushort_t* xl    = (ushort_t*)(ws + 10 * MB);
  ushort_t* xc    = (ushort_t*)(ws + 18 * MB);
  ushort_t* qb    = (ushort_t*)(ws + 34 * MB);
  ushort_t* kf    = (ushort_t*)(ws + 42 * MB);
  float*    gates = (float*)   (ws + 74 * MB);
  ushort_t* ftp   = (ushort_t*)(ws + 75 * MB);
  ushort_t* accc  = (ushort_t*)(ws + 91 * MB);
  ushort_t* acct  = (ushort_t*)(ws + 18 * MB);
  ushort_t* vb    = (ushort_t*)(ws + 75 * MB);
  ushort_t* yb    = (ushort_t*)(ws + 10 * MB);
  float*    lat1  = (float*)   (ws + 18 * MB);
  ushort_t* h2    = (ushort_t*)(ws + 34 * MB);
  ushort_t* a1    = (ushort_t*)(ws + 42 * MB);

  dim3 b256(256), b512(512);
  // 1. merged prep: weight transposes + bias_cat + both LayerNorms (one dispatch)
  prep_all<<<dim3(9489), b256, 0, stream>>>(Wq, Wk, Wf, h_w, Wproj, fc1_w, fc2_w, bfv,
                                            WqT, WkT, WfT, hwT, WpT, fc1T, fc2T, biaskf,
                                            latents, norm_l_w, norm_l_b, xl,
                                            context, norm_c_w, norm_c_b, xc);
  // 2. projections: q (gemm10) ; fused k|f (gemm11, XCD-chunked) ; gates
  gemm10<128,64, 0,0,0,1><<<dim3(64, 8), b256, 0, stream>>>(xl, WqT, nullptr, nullptr, qb, 512, 512);
  gemm11<0,1,0,1><<<dim3(4096), b256, 0, stream>>>(xc, WkT, biaskf, nullptr, kf, 1024, 512, 16);
  gates_kernel<<<dim3(4096), b256, 0, stream>>>(xc, WfT, bfv, gates);
  // 3. focal modulation branch
  tr_bf16<<<dim3(16, 8, 16), b256, 0, stream>>>(kf + 512, ftp, 1024, 512, 1024, (size_t)1024*1024, (size_t)512*1024);
  focal_conv<<<dim3(8192), b256, 0, stream>>>(ftp, gates, fk0, fk1, accc);
  tr_bf16<<<dim3(8, 16, 16), b256, 0, stream>>>(accc, acct, 512, 1024, 1024, (size_t)512*1024, (size_t)1024*512);
  gemm10<128,64, 0,1,0,1><<<dim3(128, 8), b256, 0, stream>>>(acct, hwT, h_b, nullptr, vb, 512, 512);
  // 4. attention + proj (+ residual)
  flash_attn<<<dim3(512), b512, 0, stream>>>(qb, kf, vb, yb, 1024);
  gemm10<128,64, 0,1,1,0><<<dim3(64, 8), b256, 0, stream>>>(yb, WpT, bproj, latents, lat1, 512, 512);
  // 5. MLP (+ residual) -> d_out (f32): fc1 via gemm11, fc2 via gemm10
  ln_kernel<<<dim3(2048), b256, 0, stream>>>(lat1, norm2_w, norm2_b, h2, 8192);
  gemm11<1,1,0,1><<<dim3(4096), b256, 0, stream>>>(h2, fc1T, fc1_b, nullptr, a1, 2048, 512, 32);
  gemm10<128,64, 0,1,1,0><<<dim3(64, 8), b256, 0, stream>>>(a1, fc2T, fc2_b, lat1, d_out, 512, 2048);
  (void)in_sizes; (void)n_in; (void)out_size; (void)ws_size;
}

// Round 18
// 233.515 us; speedup vs baseline: 1.0283x; 1.0283x over previous
//
#include <hip/hip_runtime.h>
#include <hip/hip_bf16.h>
#include <math.h>

#define NB 16
#define NLAT 512
#define NCTX 1024
#define CD 512
#define NH 8
#define HD 64

typedef unsigned short ushort_t;
typedef __attribute__((ext_vector_type(8))) __bf16 bf16x8;
typedef __attribute__((ext_vector_type(8))) unsigned short u16x8;
typedef __attribute__((ext_vector_type(4))) unsigned short u16x4;
typedef __attribute__((ext_vector_type(4))) float f32x4;
typedef __attribute__((ext_vector_type(2))) unsigned int u32x2;

__device__ __forceinline__ float bf2f(unsigned short u) {
  return __uint_as_float(((unsigned int)u) << 16);
}
__device__ __forceinline__ unsigned short f2bf(float f) {
  unsigned int x = __float_as_uint(f);
  return (unsigned short)((x + 0x7fffu + ((x >> 16) & 1u)) >> 16);
}
__device__ __forceinline__ float gelu_f(float x) {
  return 0.5f * x * (1.f + erff(x * 0.70710678118654752f));
}

typedef const __attribute__((address_space(1))) unsigned int* gptr1;
typedef __attribute__((address_space(3))) unsigned int* lptr3;
__device__ __forceinline__ void gload16(const void* g, void* l) {
  __builtin_amdgcn_global_load_lds((gptr1)g, (lptr3)l, 16, 0, 0);
}
__device__ __forceinline__ u32x2 tr64(unsigned a) {
  u32x2 d;
  asm volatile("ds_read_b64_tr_b16 %0, %1" : "=v"(d) : "v"(a));
  return d;
}
// compiler-invisible global->LDS staging (proven r6): m0 = wave-uniform LDS base.
__device__ __forceinline__ void gload16_asm(const void* g, unsigned lds_uniform_base) {
  unsigned sb = __builtin_amdgcn_readfirstlane(lds_uniform_base);
  asm volatile("s_mov_b32 m0, %0\n"
               "global_load_lds_dwordx4 %1, off"
               :: "s"(sb), "v"(g) : "memory");
}
template<int N> __device__ __forceinline__ void vmwait() {
  if constexpr (N == 0)       asm volatile("s_waitcnt vmcnt(0)" ::: "memory");
  else if constexpr (N == 2)  asm volatile("s_waitcnt vmcnt(2)" ::: "memory");
  else if constexpr (N == 3)  asm volatile("s_waitcnt vmcnt(3)" ::: "memory");
  else if constexpr (N == 4)  asm volatile("s_waitcnt vmcnt(4)" ::: "memory");
  else if constexpr (N == 6)  asm volatile("s_waitcnt vmcnt(6)" ::: "memory");
  else if constexpr (N == 8)  asm volatile("s_waitcnt vmcnt(8)" ::: "memory");
  else if constexpr (N == 9)  asm volatile("s_waitcnt vmcnt(9)" ::: "memory");
}

// ---------------- merged weight prep: all 7 transposes + bias_cat in one dispatch
__global__ __launch_bounds__(256)
void wprep(const float* __restrict__ Wq, const float* __restrict__ Wk,
           const float* __restrict__ Wf, const float* __restrict__ hw_,
           const float* __restrict__ Wp, const float* __restrict__ f1,
           const float* __restrict__ f2, const float* __restrict__ bfv,
           ushort_t* __restrict__ WqT, ushort_t* __restrict__ WkT,
           ushort_t* __restrict__ WfT, ushort_t* __restrict__ hwT,
           ushort_t* __restrict__ WpT, ushort_t* __restrict__ fc1T,
           ushort_t* __restrict__ fc2T, float* __restrict__ biaskf) {
  int b = blockIdx.x;
  if (b >= 3344) {   // bias_cat tail
    int i = threadIdx.x;
#pragma unroll
    for (int j = 0; j < 4; j++) {
      int idx = j * 256 + i;
      biaskf[idx] = (idx < 512) ? 0.f : bfv[idx - 512];
    }
    return;
  }
  const float* W; ushort_t* WT; int K, N, tile;
  if (b < 256)       { W = Wq;  WT = WqT;  K = 512;  N = 512;  tile = b; }
  else if (b < 512)  { W = Wk;  WT = WkT;  K = 512;  N = 512;  tile = b - 256; }
  else if (b < 784)  { W = Wf;  WT = WfT;  K = 512;  N = 515;  tile = b - 512; }
  else if (b < 1040) { W = hw_; WT = hwT;  K = 512;  N = 512;  tile = b - 784; }
  else if (b < 1296) { W = Wp;  WT = WpT;  K = 512;  N = 512;  tile = b - 1040; }
  else if (b < 2320) { W = f1;  WT = fc1T; K = 512;  N = 2048; tile = b - 1296; }
  else               { W = f2;  WT = fc2T; K = 2048; N = 512;  tile = b - 2320; }
  int Kt = K >> 5;
  int kb = (tile % Kt) * 32, nb = (tile / Kt) * 32;
  __shared__ float ts[32][33];
  int tx = threadIdx.x & 31, ty = threadIdx.x >> 5;
  for (int i = ty; i < 32; i += 8) {
    int k = kb + i, n = nb + tx;
    ts[i][tx] = (k < K && n < N) ? W[(size_t)k * N + n] : 0.f;
  }
  __syncthreads();
  for (int i = ty; i < 32; i += 8) {
    int n = nb + i, k = kb + tx;
    if (n < N && k < K) WT[(size_t)n * K + k] = f2bf(ts[tx][i]);
  }
}

// ---------------- LayerNorm (rows of 512), f32 in -> bf16 out. one wave per row.
__global__ __launch_bounds__(256)
void ln_kernel(const float* __restrict__ x, const float* __restrict__ gw,
               const float* __restrict__ gb, ushort_t* __restrict__ out, int nrows) {
  int row = blockIdx.x * 4 + (threadIdx.x >> 6);
  int lane = threadIdx.x & 63;
  const float4* xr = (const float4*)(x + (size_t)row * CD);
  float4 a = xr[lane * 2], b = xr[lane * 2 + 1];
  float s  = a.x + a.y + a.z + a.w + b.x + b.y + b.z + b.w;
  float s2 = a.x*a.x + a.y*a.y + a.z*a.z + a.w*a.w + b.x*b.x + b.y*b.y + b.z*b.z + b.w*b.w;
  for (int off = 32; off; off >>= 1) { s += __shfl_xor(s, off); s2 += __shfl_xor(s2, off); }
  float mean = s * (1.f / CD);
  float inv = rsqrtf(s2 * (1.f / CD) - mean * mean + 1e-5f);
  const float4* wv = (const float4*)gw;
  const float4* bv = (const float4*)gb;
  float4 w0 = wv[lane*2], w1 = wv[lane*2+1], c0 = bv[lane*2], c1 = bv[lane*2+1];
  u16x8 o;
  o[0] = f2bf((a.x - mean) * inv * w0.x + c0.x);
  o[1] = f2bf((a.y - mean) * inv * w0.y + c0.y);
  o[2] = f2bf((a.z - mean) * inv * w0.z + c0.z);
  o[3] = f2bf((a.w - mean) * inv * w0.w + c0.w);
  o[4] = f2bf((b.x - mean) * inv * w1.x + c1.x);
  o[5] = f2bf((b.y - mean) * inv * w1.y + c1.y);
  o[6] = f2bf((b.z - mean) * inv * w1.z + c1.z);
  o[7] = f2bf((b.w - mean) * inv * w1.w + c1.w);
  *(u16x8*)(out + (size_t)row * CD + lane * 8) = o;
  (void)nrows;
}

// ---------------- bf16 MFMA GEMM v10: 128x64 block, BK=32, 4-slot ring,
// TWO slots per barrier pair (16 MFMA + 12 ds_read between barriers),
// full-bank swizzle seg' = seg ^ ((row>>1)&3).
template<int BM, int BN, int ACT_GELU, int HAS_BIAS, int HAS_RES, int OUT_BF16>
__global__ __launch_bounds__(256)
void gemm10(const ushort_t* __restrict__ A, const ushort_t* __restrict__ BT,
            const float* __restrict__ bias, const float* __restrict__ res,
            void* __restrict__ outp, int N, int K) {
  constexpr int TM = BM / 2, FM = TM / 16;
  constexpr int TN = BN / 2, FN = TN / 16;
  constexpr int LA = BM / 64, LB = BN / 64, L = LA + LB;
  constexpr int SLOT = (BM + BN) * 32;     // ushorts per slot
  __shared__ __attribute__((aligned(16))) ushort_t SH[4][SLOT];

  const int t = threadIdx.x;
  const int lane = t & 63;
  const int wv = t >> 6;
  const int wr = wv >> 1, wc = wv & 1;
  const int g = lane >> 4, l15 = lane & 15;
  const int xsw = (g ^ ((l15 >> 1) & 3)) * 8;   // full-bank fragment col
  const size_t m0 = (size_t)blockIdx.x * BM;
  const size_t n0 = (size_t)blockIdx.y * BN;
  const int nK = K >> 5;                        // even for all our shapes

  f32x4 acc[FM][FN] = {};

  const ushort_t* Abase = A + m0 * K;
  const ushort_t* Bbase = BT + n0 * K;
  const unsigned shb = (unsigned)(size_t)(lptr3)&SH[0][0];
  const unsigned wofs = (unsigned)wv * 1024;

  auto stage = [&](int s, int kt) {
    const unsigned sb = shb + (unsigned)s * (SLOT * 2);
    const ushort_t* As = Abase + (size_t)kt * 32;
#pragma unroll
    for (int i = 0; i < LA; i++) {
      int li = i * 256 + t;
      int sc = ((li & 3) ^ ((li >> 3) & 3)) * 8;   // row = li>>2; seg' = seg^((row>>1)&3)
      gload16_asm(As + (size_t)(li >> 2) * K + sc, sb + (unsigned)i * 4096 + wofs);
    }
    const ushort_t* Bs = Bbase + (size_t)kt * 32;
#pragma unroll
    for (int i = 0; i < LB; i++) {
      int li = i * 256 + t;
      int sc = ((li & 3) ^ ((li >> 3) & 3)) * 8;
      gload16_asm(Bs + (size_t)(li >> 2) * K + sc, sb + (unsigned)(BM * 64) + (unsigned)i * 4096 + wofs);
    }
  };

  auto compute = [&](int s) {
    const ushort_t* base = &SH[0][0] + s * SLOT;
    const ushort_t* Ab = base + wr * TM * 32;
    const ushort_t* Bb = base + BM * 32 + wc * TN * 32;
    bf16x8 Bf[FN], Af[FM];
#pragma unroll
    for (int n = 0; n < FN; n++)
      Bf[n] = *(const bf16x8*)(Bb + (n * 16 + l15) * 32 + xsw);
#pragma unroll
    for (int m = 0; m < FM; m++)
      Af[m] = *(const bf16x8*)(Ab + (m * 16 + l15) * 32 + xsw);
    __builtin_amdgcn_s_setprio(1);
#pragma unroll
    for (int m = 0; m < FM; m++)
#pragma unroll
      for (int n = 0; n < FN; n++)
        acc[m][n] = __builtin_amdgcn_mfma_f32_16x16x32_bf16(Af[m], Bf[n], acc[m][n], 0, 0, 0);
    __builtin_amdgcn_s_setprio(0);
  };

  // prologue: slots 0,1 in flight; loop processes pairs (kt, kt+1)
  stage(0, 0); stage(1, 1);
  for (int kt = 0; kt < nK; kt += 2) {
    if (kt + 2 < nK) {
      stage((kt + 2) & 3, kt + 2);
      stage((kt + 3) & 3, kt + 3);
      vmwait<2 * L>();      // kt,kt+1 landed; kt+2,kt+3 in flight
    } else {
      vmwait<0>();          // last pair
    }
    __builtin_amdgcn_s_barrier();
    __builtin_amdgcn_sched_barrier(0);
    compute(kt & 3);
    compute((kt + 1) & 3);
    __builtin_amdgcn_sched_barrier(0);
    __builtin_amdgcn_s_barrier();   // slots (kt,kt+1)&3 safe to overwrite next iter
  }

  const int colb = (int)n0 + wc * TN;
  float bv[FN];
#pragma unroll
  for (int n = 0; n < FN; n++) bv[n] = HAS_BIAS ? bias[colb + n * 16 + l15] : 0.f;

  if (OUT_BF16) {
    constexpr int ES = TN + 8;
    ushort_t* ep = &SH[0][0] + wv * (TM * ES);
#pragma unroll
    for (int m = 0; m < FM; m++)
#pragma unroll
      for (int n = 0; n < FN; n++)
#pragma unroll
        for (int r = 0; r < 4; r++) {
          float v = acc[m][n][r] + bv[n];
          if (ACT_GELU) v = gelu_f(v);
          ep[(m * 16 + g * 4 + r) * ES + n * 16 + l15] = f2bf(v);
        }
    asm volatile("s_waitcnt lgkmcnt(0)" ::: "memory");
    __builtin_amdgcn_sched_barrier(0);
    const size_t gr0 = m0 + wr * TM;
#pragma unroll
    for (int c = 0; c < TM * TN / 512; c++) {
      int idx = c * 512 + lane * 8;
      int lr = idx / TN, col = idx % TN;
      u16x8 vvv = *(const u16x8*)&ep[lr * ES + col];
      *(u16x8*)((ushort_t*)outp + (gr0 + lr) * N + colb + col) = vvv;
    }
  } else {
    const int rowb = (int)m0 + wr * TM + g * 4;
#pragma unroll
    for (int n = 0; n < FN; n++) {
      int col = colb + n * 16 + l15;
#pragma unroll
      for (int m = 0; m < FM; m++) {
#pragma unroll
        for (int r = 0; r < 4; r++) {
          size_t idx = (size_t)(rowb + m * 16 + r) * N + col;
          float v = acc[m][n][r] + bv[n];
          if (ACT_GELU) v = gelu_f(v);
          if (HAS_RES) v += res[idx];
          ((float*)outp)[idx] = v;
        }
      }
    }
  }
}

// ---------------- gates: 3 matvec outputs per context row -> (B,3,HW) f32
__global__ __launch_bounds__(256)
void gates_kernel(const ushort_t* __restrict__ xc, const ushort_t* __restrict__ WfT,
                  const float* __restrict__ bfv, float* __restrict__ gates) {
  int row = blockIdx.x * 4 + (threadIdx.x >> 6);
  int lane = threadIdx.x & 63;
  u16x8 xv = *(const u16x8*)(xc + (size_t)row * CD + lane * 8);
  float xf[8];
#pragma unroll
  for (int e = 0; e < 8; e++) xf[e] = bf2f(xv[e]);
  float sl[3];
#pragma unroll
  for (int l = 0; l < 3; l++) {
    u16x8 wvv = *(const u16x8*)(WfT + (size_t)(CD + l) * CD + lane * 8);
    float d = 0.f;
#pragma unroll
    for (int e = 0; e < 8; e++) d += xf[e] * bf2f(wvv[e]);
    for (int off = 32; off; off >>= 1) d += __shfl_xor(d, off);
    sl[l] = d;
  }
  if (lane == 0) {
    int b = row >> 10, p = row & 1023;
#pragma unroll
    for (int l = 0; l < 3; l++) gates[((size_t)b * 3 + l) * 1024 + p] = sl[l] + bfv[CD + l];
  }
}

// ---------------- bf16 transpose per batch: out[b][c][r] = in[b*ibs + r*irs + c]
__global__ __launch_bounds__(256)
void tr_bf16(const ushort_t* __restrict__ in, ushort_t* __restrict__ out, int R, int C,
             int irs, size_t ibs, size_t obs) {
  __shared__ ushort_t tile[64][72];
  size_t ibase = (size_t)blockIdx.z * ibs;
  size_t obase = (size_t)blockIdx.z * obs;
  int r0 = blockIdx.x * 64, c0 = blockIdx.y * 64;
  int t = threadIdx.x;
#pragma unroll
  for (int j = 0; j < 2; j++) {
    int lin = j * 256 + t;
    int r = lin >> 3, cc = (lin & 7) * 8;
    u16x8 v = *(const u16x8*)(in + ibase + (size_t)(r0 + r) * irs + c0 + cc);
#pragma unroll
    for (int e = 0; e < 8; e++) tile[r][cc + e] = v[e];
  }
  __syncthreads();
#pragma unroll
  for (int j = 0; j < 2; j++) {
    int lin = j * 256 + t;
    int c = lin >> 3, rr = (lin & 7) * 8;
    u16x8 v;
#pragma unroll
    for (int e = 0; e < 8; e++) v[e] = tile[rr + e][c];
    *(u16x8*)(out + obase + (size_t)(c0 + c) * R + r0 + rr) = v;
  }
}

// ---------------- focal conv v2: zero-padded LDS halos, branch-free FMA chains,
// 4 consecutive px/thread (u16x4/float4 vector IO), odd LDS strides.
__global__ __launch_bounds__(256)
void focal_conv(const ushort_t* __restrict__ ft, const float* __restrict__ gates,
                const float* __restrict__ fk0, const float* __restrict__ fk1,
                ushort_t* __restrict__ accc) {
  int bc = blockIdx.x;
  int b = bc >> 9, c = bc & 511;
  __shared__ float xs[34][37];
  __shared__ float vs[38][41];
  __shared__ float w0s[9], w1s[25];
  __shared__ float red[4];
  const int t = threadIdx.x;
  const int hh = t >> 3;
  const int w0c = (t & 7) * 4;

  float* xz = &xs[0][0];
  float* vz = &vs[0][0];
#pragma unroll
  for (int i = 0; i < 5; i++) { int idx = t + i * 256; if (idx < 34 * 37) xz[idx] = 0.f; }
#pragma unroll
  for (int i = 0; i < 7; i++) { int idx = t + i * 256; if (idx < 38 * 41) vz[idx] = 0.f; }
  if (t < 9)  w0s[t] = fk0[c * 9 + t];
  if (t < 25) w1s[t] = fk1[c * 25 + t];

  u16x4 vin = *(const u16x4*)(ft + (size_t)bc * 1024 + t * 4);
  const float* g0 = gates + (size_t)b * 3 * 1024;
  float4 ga = *(const float4*)(g0 + t * 4);
  float4 gb = *(const float4*)(g0 + 1024 + t * 4);
  float4 gc = *(const float4*)(g0 + 2048 + t * 4);
  __syncthreads();
#pragma unroll
  for (int j = 0; j < 4; j++) xs[hh + 1][w0c + 1 + j] = bf2f(vin[j]);
  __syncthreads();

  float accv[4];
  const float* gav = (const float*)&ga;
  const float* gbv = (const float*)&gb;
  const float* gcv = (const float*)&gc;
#pragma unroll
  for (int j = 0; j < 4; j++) {
    int ww = w0c + j;
    float s = 0.f;
#pragma unroll
    for (int dh = 0; dh < 3; dh++)
#pragma unroll
      for (int dw = 0; dw < 3; dw++)
        s += xs[hh + dh][ww + dw] * w0s[dh * 3 + dw];
    float v1 = gelu_f(s);
    vs[hh + 2][ww + 2] = v1;
    accv[j] = v1 * gav[j];
  }
  __syncthreads();

  float psum = 0.f;
#pragma unroll
  for (int j = 0; j < 4; j++) {
    int ww = w0c + j;
    float s = 0.f;
#pragma unroll
    for (int dh = 0; dh < 5; dh++)
#pragma unroll
      for (int dw = 0; dw < 5; dw++)
        s += vs[hh + dh][ww + dw] * w1s[dh * 5 + dw];
    float v2 = gelu_f(s);
    psum += v2;
    accv[j] += v2 * gbv[j];
  }
  for (int off = 32; off; off >>= 1) psum += __shfl_xor(psum, off);
  if ((t & 63) == 0) red[t >> 6] = psum;
  __syncthreads();
  float g = gelu_f((red[0] + red[1] + red[2] + red[3]) * (1.f / 1024.f));
  u16x4 o;
#pragma unroll
  for (int j = 0; j < 4; j++) o[j] = f2bf(accv[j] + g * gcv[j]);
  *(u16x4*)(accc + (size_t)bc * 1024 + t * 4) = o;
}

// ---------------- flash attention v3: no-max softmax, deferred denominator,
// batched tr64, XCD swizzle.
__global__ __launch_bounds__(512)
void flash_attn(const ushort_t* __restrict__ Q, const ushort_t* __restrict__ Kk,
                const ushort_t* __restrict__ V, ushort_t* __restrict__ Y, int kstride) {
  const int wg = blockIdx.x;
  const int swz = (wg & 7) * 64 + (wg >> 3);
  const int q0 = (swz & 3) * 128;
  const int h = (swz >> 2) & 7;
  const int b = swz >> 5;
  const int t = threadIdx.x, lane = t & 63, w = t >> 6;
  const int g = lane >> 4, l15 = lane & 15;
  __shared__ __attribute__((aligned(16))) ushort_t Ks[2][4096];
  __shared__ __attribute__((aligned(16))) ushort_t Vs[2][4096];
  __shared__ __attribute__((aligned(16))) ushort_t Ps[8][1024];

  const size_t qbase = (((size_t)b * NLAT) + q0 + w * 16 + l15) * CD + h * HD;
  bf16x8 aq[2];
#pragma unroll
  for (int kk = 0; kk < 2; kk++) {
    u16x8 u = *(const u16x8*)(Q + qbase + kk * 32 + g * 8);
    u16x8 o;
#pragma unroll
    for (int e = 0; e < 8; e++) o[e] = f2bf(bf2f(u[e]) * 0.125f);
    aq[kk] = *(bf16x8*)&o;
  }

  f32x4 accO[4] = {};
  float lsum[4] = {0.f, 0.f, 0.f, 0.f};
  const ushort_t* Kb = Kk + ((size_t)b * NCTX) * kstride + h * HD;
  const ushort_t* Vb = V  + ((size_t)b * NCTX) * CD + h * HD;
  const int krow = t >> 3;
  const int kseg = 8 * ((t & 7) ^ (krow & 7));
  const int vrow = (t >> 1) & 63;
  const int vcol = (t >> 7) * 16 + (t & 1) * 8;

  auto stage = [&](int buf, int kv) {
    const int k0 = kv * 64;
    gload16(Kb + (size_t)(k0 + krow) * kstride + kseg, &Ks[buf][t * 8]);
    gload16(Vb + (size_t)(k0 + vrow) * CD + vcol, &Vs[buf][t * 8]);
  };

  const unsigned vsbase0 = (unsigned)(size_t)(lptr3)&Vs[0][0];
  const unsigned vsbase1 = (unsigned)(size_t)(lptr3)&Vs[1][0];
  char* psb = (char*)&Ps[w][0];

  stage(0, 0);
  __syncthreads();
  int cur = 0;
  for (int kv = 0; kv < 16; kv++) {
    if (kv < 15) stage(cur ^ 1, kv + 1);

    const char* ksb = (const char*)&Ks[cur][0];
    f32x4 accS[4] = {};
#pragma unroll
    for (int kk = 0; kk < 2; kk++) {
#pragma unroll
      for (int n = 0; n < 4; n++) {
        int rr = n * 16 + l15;
        bf16x8 bk = *(const bf16x8*)(ksb + rr * 128 + ((kk * 64 + g * 16) ^ ((rr & 7) << 4)));
        accS[n] = __builtin_amdgcn_mfma_f32_16x16x32_bf16(aq[kk], bk, accS[n], 0, 0, 0);
      }
    }

#pragma unroll
    for (int n = 0; n < 4; n++)
#pragma unroll
      for (int r = 0; r < 4; r++) {
        float p = __expf(accS[n][r]);
        accS[n][r] = p;
        lsum[r] += p;
      }

#pragma unroll
    for (int n = 0; n < 4; n++)
#pragma unroll
      for (int r = 0; r < 4; r++) {
        int row = g * 4 + r;
        int cb = (n * 16 + l15) * 2;
        *(ushort_t*)(psb + row * 128 + (cb ^ ((row & 7) << 4))) = f2bf(accS[n][r]);
      }
    asm volatile("s_waitcnt lgkmcnt(0)" ::: "memory");
    __builtin_amdgcn_sched_barrier(0);
    bf16x8 ap0 = *(const bf16x8*)(psb + l15 * 128 + (((g * 16)) ^ ((l15 & 7) << 4)));
    bf16x8 ap1 = *(const bf16x8*)(psb + l15 * 128 + ((64 + g * 16) ^ ((l15 & 7) << 4)));

    const unsigned vsb = (cur ? vsbase1 : vsbase0) + g * 128;
    union PKU { u32x2 d2[2]; bf16x8 v; };
    PKU pk[8];
#pragma unroll
    for (int n = 0; n < 4; n++) {
      unsigned a = vsb + n * 2048;
      pk[n * 2].d2[0]     = tr64(a);
      pk[n * 2].d2[1]     = tr64(a + 128);
      pk[n * 2 + 1].d2[0] = tr64(a + 1024);
      pk[n * 2 + 1].d2[1] = tr64(a + 1152);
    }
    asm volatile("s_waitcnt lgkmcnt(0)" ::: "memory");
    __builtin_amdgcn_sched_barrier(0);
#pragma unroll
    for (int n = 0; n < 4; n++) {
      accO[n] = __builtin_amdgcn_mfma_f32_16x16x32_bf16(ap0, pk[n * 2].v, accO[n], 0, 0, 0);
      accO[n] = __builtin_amdgcn_mfma_f32_16x16x32_bf16(ap1, pk[n * 2 + 1].v, accO[n], 0, 0, 0);
    }
    __syncthreads();
    cur ^= 1;
  }

#pragma unroll
  for (int r = 0; r < 4; r++) {
    float s = lsum[r];
    s += __shfl_xor(s, 1); s += __shfl_xor(s, 2);
    s += __shfl_xor(s, 4); s += __shfl_xor(s, 8);
    lsum[r] = 1.f / s;
  }
#pragma unroll
  for (int n = 0; n < 4; n++) {
#pragma unroll
    for (int r = 0; r < 4; r++) {
      size_t row = q0 + w * 16 + g * 4 + r;
      size_t col = h * HD + n * 16 + l15;
      Y[(((size_t)b * NLAT) + row) * CD + col] = f2bf(accO[n][r] * lsum[r]);
    }
  }
}

// ---------------- host orchestration
extern "C" void kernel_launch(void* const* d_in, const int* in_sizes, int n_in,
                              void* d_out, int out_size, void* d_ws, size_t ws_size,
                              hipStream_t stream) {
  const float* latents  = (const float*)d_in[0];
  const float* context  = (const float*)d_in[1];
  const float* norm_l_w = (const float*)d_in[4];
  const float* norm_l_b = (const float*)d_in[5];
  const float* norm_c_w = (const float*)d_in[6];
  const float* norm_c_b = (const float*)d_in[7];
  const float* norm2_w  = (const float*)d_in[8];
  const float* norm2_b  = (const float*)d_in[9];
  const float* Wq    = (const float*)d_in[10];
  const float* Wk    = (const float*)d_in[11];
  const float* Wf    = (const float*)d_in[12];
  const float* bfv   = (const float*)d_in[13];
  const float* fk0   = (const float*)d_in[14];
  const float* fk1   = (const float*)d_in[15];
  const float* h_w   = (const float*)d_in[16];
  const float* h_b   = (const float*)d_in[17];
  const float* Wproj = (const float*)d_in[18];
  const float* bproj = (const float*)d_in[19];
  const float* fc1_w = (const float*)d_in[20];
  const float* fc1_b = (const float*)d_in[21];
  const float* fc2_w = (const float*)d_in[22];
  const float* fc2_b = (const float*)d_in[23];

  char* ws = (char*)d_ws;
  const size_t MB = 1024ull * 1024ull;
  ushort_t* WqT  = (ushort_t*)(ws + 0 * MB);
  ushort_t* WkT  = (ushort_t*)(ws + 1 * MB);
  ushort_t* WfT  = (ushort_t*)(ws + 1 * MB + 524288);
  ushort_t* hwT  = (ushort_t*)(ws + 3 * MB);
  ushort_t* WpT  = (ushort_t*)(ws + 4 * MB);
  ushort_t* fc1T = (ushort_t*)(ws + 5 * MB);
  ushort_t* fc2T = (ushort_t*)(ws + 7 * MB);
  float*    biaskf = (float*)(ws + 9 * MB);
  ushort_t* xl    = (ushort_t*)(ws + 10 * MB);
  ushort_t* xc    = (ushort_t*)(ws + 18 * MB);
  ushort_t* qb    = (ushort_t*)(ws + 34 * MB);
  ushort_t* kf    = (ushort_t*)(ws + 42 * MB);
  float*    gates = (float*)   (ws + 74 * MB);
  ushort_t* ftp   = (ushort_t*)(ws + 75 * MB);
  ushort_t* accc  = (ushort_t*)(ws + 91 * MB);
  ushort_t* acct  = (ushort_t*)(ws + 18 * MB);
  ushort_t* vb    = (ushort_t*)(ws + 75 * MB);
  ushort_t* yb    = (ushort_t*)(ws + 10 * MB);
  float*    lat1  = (float*)   (ws + 18 * MB);
  ushort_t* h2    = (ushort_t*)(ws + 34 * MB);
  ushort_t* a1    = (ushort_t*)(ws + 42 * MB);

  dim3 b256(256), b512(512);
  // 1. weight prep (single dispatch)
  wprep<<<dim3(3345), b256, 0, stream>>>(Wq, Wk, Wf, h_w, Wproj, fc1_w, fc2_w, bfv,
                                         WqT, WkT, WfT, hwT, WpT, fc1T, fc2T, biaskf);
  // 2. layernorms
  ln_kernel<<<dim3(2048), b256, 0, stream>>>(latents, norm_l_w, norm_l_b, xl, 8192);
  ln_kernel<<<dim3(4096), b256, 0, stream>>>(context, norm_c_w, norm_c_b, xc, 16384);
  // 3. projections: q ; fused k|f ; gates
  gemm10<128,64, 0,0,0,1><<<dim3(64, 8),   b256, 0, stream>>>(xl, WqT, nullptr, nullptr, qb, 512, 512);
  gemm10<128,64, 0,1,0,1><<<dim3(128, 16), b256, 0, stream>>>(xc, WkT, biaskf, nullptr, kf, 1024, 512);
  gates_kernel<<<dim3(4096), b256, 0, stream>>>(xc, WfT, bfv, gates);
  // 4. focal modulation branch
  tr_bf16<<<dim3(16, 8, 16), b256, 0, stream>>>(kf + 512, ftp, 1024, 512, 1024, (size_t)1024*1024, (size_t)512*1024);
  focal_conv<<<dim3(8192), b256, 0, stream>>>(ftp, gates, fk0, fk1, accc);
  tr_bf16<<<dim3(8, 16, 16), b256, 0, stream>>>(accc, acct, 512, 1024, 1024, (size_t)512*1024, (size_t)1024*512);
  gemm10<128,64, 0,1,0,1><<<dim3(128, 8), b256, 0, stream>>>(acct, hwT, h_b, nullptr, vb, 512, 512);
  // 5. attention + proj (+ residual)
  flash_attn<<<dim3(512), b512, 0, stream>>>(qb, kf, vb, yb, 1024);
  gemm10<128,64, 0,1,1,0><<<dim3(64, 8), b256, 0, stream>>>(yb, WpT, bproj, latents, lat1, 512, 512);
  // 6. MLP (+ residual) -> d_out (f32)
  ln_kernel<<<dim3(2048), b256, 0, stream>>>(lat1, norm2_w, norm2_b, h2, 8192);
  gemm10<128,64, 1,1,0,1><<<dim3(64, 32), b256, 0, stream>>>(h2, fc1T, fc1_b, nullptr, a1, 2048, 512);
  gemm10<128,64, 0,1,1,0><<<dim3(64, 8),  b256, 0, stream>>>(a1, fc2T, fc2_b, lat1, d_out, 512, 2048);
  (void)in_sizes; (void)n_in; (void)out_size; (void)ws_size;
}

// Round 19
// 228.683 us; speedup vs baseline: 1.0500x; 1.0211x over previous
//
#include <hip/hip_runtime.h>
#include <hip/hip_bf16.h>
#include <math.h>

#define NB 16
#define NLAT 512
#define NCTX 1024
#define CD 512
#define NH 8
#define HD 64

typedef unsigned short ushort_t;
typedef __attribute__((ext_vector_type(8))) __bf16 bf16x8;
typedef __attribute__((ext_vector_type(8))) unsigned short u16x8;
typedef __attribute__((ext_vector_type(4))) unsigned short u16x4;
typedef __attribute__((ext_vector_type(4))) float f32x4;
typedef __attribute__((ext_vector_type(2))) unsigned int u32x2;

__device__ __forceinline__ float bf2f(unsigned short u) {
  return __uint_as_float(((unsigned int)u) << 16);
}
__device__ __forceinline__ unsigned short f2bf(float f) {
  unsigned int x = __float_as_uint(f);
  return (unsigned short)((x + 0x7fffu + ((x >> 16) & 1u)) >> 16);
}
__device__ __forceinline__ float gelu_f(float x) {
  return 0.5f * x * (1.f + erff(x * 0.70710678118654752f));
}

typedef const __attribute__((address_space(1))) unsigned int* gptr1;
typedef __attribute__((address_space(3))) unsigned int* lptr3;
__device__ __forceinline__ void gload16(const void* g, void* l) {
  __builtin_amdgcn_global_load_lds((gptr1)g, (lptr3)l, 16, 0, 0);
}
__device__ __forceinline__ u32x2 tr64(unsigned a) {
  u32x2 d;
  asm volatile("ds_read_b64_tr_b16 %0, %1" : "=v"(d) : "v"(a));
  return d;
}
// compiler-invisible global->LDS staging (proven r6): m0 = wave-uniform LDS base.
__device__ __forceinline__ void gload16_asm(const void* g, unsigned lds_uniform_base) {
  unsigned sb = __builtin_amdgcn_readfirstlane(lds_uniform_base);
  asm volatile("s_mov_b32 m0, %0\n"
               "global_load_lds_dwordx4 %1, off"
               :: "s"(sb), "v"(g) : "memory");
}
template<int N> __device__ __forceinline__ void vmwait() {
  if constexpr (N == 0)       asm volatile("s_waitcnt vmcnt(0)" ::: "memory");
  else if constexpr (N == 2)  asm volatile("s_waitcnt vmcnt(2)" ::: "memory");
  else if constexpr (N == 3)  asm volatile("s_waitcnt vmcnt(3)" ::: "memory");
  else if constexpr (N == 4)  asm volatile("s_waitcnt vmcnt(4)" ::: "memory");
  else if constexpr (N == 6)  asm volatile("s_waitcnt vmcnt(6)" ::: "memory");
  else if constexpr (N == 8)  asm volatile("s_waitcnt vmcnt(8)" ::: "memory");
  else if constexpr (N == 9)  asm volatile("s_waitcnt vmcnt(9)" ::: "memory");
}

// ---------------- LN row helper (one wave per row of 512)
__device__ __forceinline__ void ln_row(const float* __restrict__ x,
                                       const float* __restrict__ gw,
                                       const float* __restrict__ gb,
                                       ushort_t* __restrict__ out,
                                       int row, int lane) {
  const float4* xr = (const float4*)(x + (size_t)row * CD);
  float4 a = xr[lane * 2], b = xr[lane * 2 + 1];
  float s  = a.x + a.y + a.z + a.w + b.x + b.y + b.z + b.w;
  float s2 = a.x*a.x + a.y*a.y + a.z*a.z + a.w*a.w + b.x*b.x + b.y*b.y + b.z*b.z + b.w*b.w;
  for (int off = 32; off; off >>= 1) { s += __shfl_xor(s, off); s2 += __shfl_xor(s2, off); }
  float mean = s * (1.f / CD);
  float inv = rsqrtf(s2 * (1.f / CD) - mean * mean + 1e-5f);
  const float4* wv = (const float4*)gw;
  const float4* bv = (const float4*)gb;
  float4 w0 = wv[lane*2], w1 = wv[lane*2+1], c0 = bv[lane*2], c1 = bv[lane*2+1];
  u16x8 o;
  o[0] = f2bf((a.x - mean) * inv * w0.x + c0.x);
  o[1] = f2bf((a.y - mean) * inv * w0.y + c0.y);
  o[2] = f2bf((a.z - mean) * inv * w0.z + c0.z);
  o[3] = f2bf((a.w - mean) * inv * w0.w + c0.w);
  o[4] = f2bf((b.x - mean) * inv * w1.x + c1.x);
  o[5] = f2bf((b.y - mean) * inv * w1.y + c1.y);
  o[6] = f2bf((b.z - mean) * inv * w1.z + c1.z);
  o[7] = f2bf((b.w - mean) * inv * w1.w + c1.w);
  *(u16x8*)(out + (size_t)row * CD + lane * 8) = o;
}

// ---------------- merged prep: 7 weight transposes + bias_cat + both input LNs
__global__ __launch_bounds__(256)
void prep_all(const float* __restrict__ Wq, const float* __restrict__ Wk,
              const float* __restrict__ Wf, const float* __restrict__ hw_,
              const float* __restrict__ Wp, const float* __restrict__ f1,
              const float* __restrict__ f2, const float* __restrict__ bfv,
              ushort_t* __restrict__ WqT, ushort_t* __restrict__ WkT,
              ushort_t* __restrict__ WfT, ushort_t* __restrict__ hwT,
              ushort_t* __restrict__ WpT, ushort_t* __restrict__ fc1T,
              ushort_t* __restrict__ fc2T, float* __restrict__ biaskf,
              const float* __restrict__ latents, const float* __restrict__ nlw,
              const float* __restrict__ nlb, ushort_t* __restrict__ xl,
              const float* __restrict__ context, const float* __restrict__ ncw,
              const float* __restrict__ ncb, ushort_t* __restrict__ xc) {
  int b = blockIdx.x;
  if (b >= 3345) {   // LayerNorm section (6144 blocks: 2048 latents + 4096 context)
    int lb = b - 3345;
    int lane = threadIdx.x & 63, wvi = threadIdx.x >> 6;
    if (lb < 2048) ln_row(latents, nlw, nlb, xl, lb * 4 + wvi, lane);
    else           ln_row(context, ncw, ncb, xc, (lb - 2048) * 4 + wvi, lane);
    return;
  }
  if (b == 3344) {   // bias_cat tail
    int i = threadIdx.x;
#pragma unroll
    for (int j = 0; j < 4; j++) {
      int idx = j * 256 + i;
      biaskf[idx] = (idx < 512) ? 0.f : bfv[idx - 512];
    }
    return;
  }
  const float* W; ushort_t* WT; int K, N, tile;
  if (b < 256)       { W = Wq;  WT = WqT;  K = 512;  N = 512;  tile = b; }
  else if (b < 512)  { W = Wk;  WT = WkT;  K = 512;  N = 512;  tile = b - 256; }
  else if (b < 784)  { W = Wf;  WT = WfT;  K = 512;  N = 515;  tile = b - 512; }
  else if (b < 1040) { W = hw_; WT = hwT;  K = 512;  N = 512;  tile = b - 784; }
  else if (b < 1296) { W = Wp;  WT = WpT;  K = 512;  N = 512;  tile = b - 1040; }
  else if (b < 2320) { W = f1;  WT = fc1T; K = 512;  N = 2048; tile = b - 1296; }
  else               { W = f2;  WT = fc2T; K = 2048; N = 512;  tile = b - 2320; }
  int Kt = K >> 5;
  int kb = (tile % Kt) * 32, nb = (tile / Kt) * 32;
  __shared__ float ts[32][33];
  int tx = threadIdx.x & 31, ty = threadIdx.x >> 5;
  for (int i = ty; i < 32; i += 8) {
    int k = kb + i, n = nb + tx;
    ts[i][tx] = (k < K && n < N) ? W[(size_t)k * N + n] : 0.f;
  }
  __syncthreads();
  for (int i = ty; i < 32; i += 8) {
    int n = nb + i, k = kb + tx;
    if (n < N && k < K) WT[(size_t)n * K + k] = f2bf(ts[tx][i]);
  }
}

// ---------------- standalone LN (for post-proj lat1 -> h2)
__global__ __launch_bounds__(256)
void ln_kernel(const float* __restrict__ x, const float* __restrict__ gw,
               const float* __restrict__ gb, ushort_t* __restrict__ out, int nrows) {
  ln_row(x, gw, gb, out, blockIdx.x * 4 + (threadIdx.x >> 6), threadIdx.x & 63);
  (void)nrows;
}

// ---------------- bf16 MFMA GEMM v10 (r14/r18-exact): 128x64 block, BK=32,
// 4-slot ring, two slots per barrier pair, full-bank swizzle seg'=seg^((row>>1)&3).
template<int BM, int BN, int ACT_GELU, int HAS_BIAS, int HAS_RES, int OUT_BF16>
__global__ __launch_bounds__(256)
void gemm10(const ushort_t* __restrict__ A, const ushort_t* __restrict__ BT,
            const float* __restrict__ bias, const float* __restrict__ res,
            void* __restrict__ outp, int N, int K) {
  constexpr int TM = BM / 2, FM = TM / 16;
  constexpr int TN = BN / 2, FN = TN / 16;
  constexpr int LA = BM / 64, LB = BN / 64, L = LA + LB;
  constexpr int SLOT = (BM + BN) * 32;     // ushorts per slot
  __shared__ __attribute__((aligned(16))) ushort_t SH[4][SLOT];

  const int t = threadIdx.x;
  const int lane = t & 63;
  const int wv = t >> 6;
  const int wr = wv >> 1, wc = wv & 1;
  const int g = lane >> 4, l15 = lane & 15;
  const int xsw = (g ^ ((l15 >> 1) & 3)) * 8;   // full-bank fragment col
  const size_t m0 = (size_t)blockIdx.x * BM;
  const size_t n0 = (size_t)blockIdx.y * BN;
  const int nK = K >> 5;

  f32x4 acc[FM][FN] = {};

  const ushort_t* Abase = A + m0 * K;
  const ushort_t* Bbase = BT + n0 * K;
  const unsigned shb = (unsigned)(size_t)(lptr3)&SH[0][0];
  const unsigned wofs = (unsigned)wv * 1024;

  auto stage = [&](int s, int kt) {
    const unsigned sb = shb + (unsigned)s * (SLOT * 2);
    const ushort_t* As = Abase + (size_t)kt * 32;
#pragma unroll
    for (int i = 0; i < LA; i++) {
      int li = i * 256 + t;
      int sc = ((li & 3) ^ ((li >> 3) & 3)) * 8;   // row = li>>2; seg' = seg^((row>>1)&3)
      gload16_asm(As + (size_t)(li >> 2) * K + sc, sb + (unsigned)i * 4096 + wofs);
    }
    const ushort_t* Bs = Bbase + (size_t)kt * 32;
#pragma unroll
    for (int i = 0; i < LB; i++) {
      int li = i * 256 + t;
      int sc = ((li & 3) ^ ((li >> 3) & 3)) * 8;
      gload16_asm(Bs + (size_t)(li >> 2) * K + sc, sb + (unsigned)(BM * 64) + (unsigned)i * 4096 + wofs);
    }
  };

  auto compute = [&](int s) {
    const ushort_t* base = &SH[0][0] + s * SLOT;
    const ushort_t* Ab = base + wr * TM * 32;
    const ushort_t* Bb = base + BM * 32 + wc * TN * 32;
    bf16x8 Bf[FN], Af[FM];
#pragma unroll
    for (int n = 0; n < FN; n++)
      Bf[n] = *(const bf16x8*)(Bb + (n * 16 + l15) * 32 + xsw);
#pragma unroll
    for (int m = 0; m < FM; m++)
      Af[m] = *(const bf16x8*)(Ab + (m * 16 + l15) * 32 + xsw);
    __builtin_amdgcn_s_setprio(1);
#pragma unroll
    for (int m = 0; m < FM; m++)
#pragma unroll
      for (int n = 0; n < FN; n++)
        acc[m][n] = __builtin_amdgcn_mfma_f32_16x16x32_bf16(Af[m], Bf[n], acc[m][n], 0, 0, 0);
    __builtin_amdgcn_s_setprio(0);
  };

  // prologue: slots 0,1 in flight; loop processes pairs (kt, kt+1)
  stage(0, 0); stage(1, 1);
  for (int kt = 0; kt < nK; kt += 2) {
    if (kt + 2 < nK) {
      stage((kt + 2) & 3, kt + 2);
      stage((kt + 3) & 3, kt + 3);
      vmwait<2 * L>();      // kt,kt+1 landed; kt+2,kt+3 in flight
    } else {
      vmwait<0>();          // last pair
    }
    __builtin_amdgcn_s_barrier();
    __builtin_amdgcn_sched_barrier(0);
    compute(kt & 3);
    compute((kt + 1) & 3);
    __builtin_amdgcn_sched_barrier(0);
    __builtin_amdgcn_s_barrier();   // slots (kt,kt+1)&3 safe to overwrite next iter
  }

  const int colb = (int)n0 + wc * TN;
  float bv[FN];
#pragma unroll
  for (int n = 0; n < FN; n++) bv[n] = HAS_BIAS ? bias[colb + n * 16 + l15] : 0.f;

  if (OUT_BF16) {
    constexpr int ES = TN + 8;
    ushort_t* ep = &SH[0][0] + wv * (TM * ES);
#pragma unroll
    for (int m = 0; m < FM; m++)
#pragma unroll
      for (int n = 0; n < FN; n++)
#pragma unroll
        for (int r = 0; r < 4; r++) {
          float v = acc[m][n][r] + bv[n];
          if (ACT_GELU) v = gelu_f(v);
          ep[(m * 16 + g * 4 + r) * ES + n * 16 + l15] = f2bf(v);
        }
    asm volatile("s_waitcnt lgkmcnt(0)" ::: "memory");
    __builtin_amdgcn_sched_barrier(0);
    const size_t gr0 = m0 + wr * TM;
#pragma unroll
    for (int c = 0; c < TM * TN / 512; c++) {
      int idx = c * 512 + lane * 8;
      int lr = idx / TN, col = idx % TN;
      u16x8 vvv = *(const u16x8*)&ep[lr * ES + col];
      *(u16x8*)((ushort_t*)outp + (gr0 + lr) * N + colb + col) = vvv;
    }
  } else {
    const int rowb = (int)m0 + wr * TM + g * 4;
#pragma unroll
    for (int n = 0; n < FN; n++) {
      int col = colb + n * 16 + l15;
#pragma unroll
      for (int m = 0; m < FM; m++) {
#pragma unroll
        for (int r = 0; r < 4; r++) {
          size_t idx = (size_t)(rowb + m * 16 + r) * N + col;
          float v = acc[m][n][r] + bv[n];
          if (ACT_GELU) v = gelu_f(v);
          if (HAS_RES) v += res[idx];
          ((float*)outp)[idx] = v;
        }
      }
    }
  }
}

// ---------------- gates: 3 matvec outputs per context row -> (B,3,HW) f32
__global__ __launch_bounds__(256)
void gates_kernel(const ushort_t* __restrict__ xc, const ushort_t* __restrict__ WfT,
                  const float* __restrict__ bfv, float* __restrict__ gates) {
  int row = blockIdx.x * 4 + (threadIdx.x >> 6);
  int lane = threadIdx.x & 63;
  u16x8 xv = *(const u16x8*)(xc + (size_t)row * CD + lane * 8);
  float xf[8];
#pragma unroll
  for (int e = 0; e < 8; e++) xf[e] = bf2f(xv[e]);
  float sl[3];
#pragma unroll
  for (int l = 0; l < 3; l++) {
    u16x8 wvv = *(const u16x8*)(WfT + (size_t)(CD + l) * CD + lane * 8);
    float d = 0.f;
#pragma unroll
    for (int e = 0; e < 8; e++) d += xf[e] * bf2f(wvv[e]);
    for (int off = 32; off; off >>= 1) d += __shfl_xor(d, off);
    sl[l] = d;
  }
  if (lane == 0) {
    int b = row >> 10, p = row & 1023;
#pragma unroll
    for (int l = 0; l < 3; l++) gates[((size_t)b * 3 + l) * 1024 + p] = sl[l] + bfv[CD + l];
  }
}

// ---------------- bf16 transpose per batch: out[b][c][r] = in[b*ibs + r*irs + c]
__global__ __launch_bounds__(256)
void tr_bf16(const ushort_t* __restrict__ in, ushort_t* __restrict__ out, int R, int C,
             int irs, size_t ibs, size_t obs) {
  __shared__ ushort_t tile[64][72];
  size_t ibase = (size_t)blockIdx.z * ibs;
  size_t obase = (size_t)blockIdx.z * obs;
  int r0 = blockIdx.x * 64, c0 = blockIdx.y * 64;
  int t = threadIdx.x;
#pragma unroll
  for (int j = 0; j < 2; j++) {
    int lin = j * 256 + t;
    int r = lin >> 3, cc = (lin & 7) * 8;
    u16x8 v = *(const u16x8*)(in + ibase + (size_t)(r0 + r) * irs + c0 + cc);
#pragma unroll
    for (int e = 0; e < 8; e++) tile[r][cc + e] = v[e];
  }
  __syncthreads();
#pragma unroll
  for (int j = 0; j < 2; j++) {
    int lin = j * 256 + t;
    int c = lin >> 3, rr = (lin & 7) * 8;
    u16x8 v;
#pragma unroll
    for (int e = 0; e < 8; e++) v[e] = tile[rr + e][c];
    *(u16x8*)(out + obase + (size_t)(c0 + c) * R + r0 + rr) = v;
  }
}

// ---------------- focal conv v2: zero-padded LDS halos, branch-free FMA chains,
// 4 consecutive px/thread (u16x4/float4 vector IO), odd LDS strides.
__global__ __launch_bounds__(256)
void focal_conv(const ushort_t* __restrict__ ft, const float* __restrict__ gates,
                const float* __restrict__ fk0, const float* __restrict__ fk1,
                ushort_t* __restrict__ accc) {
  int bc = blockIdx.x;
  int b = bc >> 9, c = bc & 511;
  __shared__ float xs[34][37];
  __shared__ float vs[38][41];
  __shared__ float w0s[9], w1s[25];
  __shared__ float red[4];
  const int t = threadIdx.x;
  const int hh = t >> 3;
  const int w0c = (t & 7) * 4;

  float* xz = &xs[0][0];
  float* vz = &vs[0][0];
#pragma unroll
  for (int i = 0; i < 5; i++) { int idx = t + i * 256; if (idx < 34 * 37) xz[idx] = 0.f; }
#pragma unroll
  for (int i = 0; i < 7; i++) { int idx = t + i * 256; if (idx < 38 * 41) vz[idx] = 0.f; }
  if (t < 9)  w0s[t] = fk0[c * 9 + t];
  if (t < 25) w1s[t] = fk1[c * 25 + t];

  u16x4 vin = *(const u16x4*)(ft + (size_t)bc * 1024 + t * 4);
  const float* g0 = gates + (size_t)b * 3 * 1024;
  float4 ga = *(const float4*)(g0 + t * 4);
  float4 gb = *(const float4*)(g0 + 1024 + t * 4);
  float4 gc = *(const float4*)(g0 + 2048 + t * 4);
  __syncthreads();
#pragma unroll
  for (int j = 0; j < 4; j++) xs[hh + 1][w0c + 1 + j] = bf2f(vin[j]);
  __syncthreads();

  float accv[4];
  const float* gav = (const float*)&ga;
  const float* gbv = (const float*)&gb;
  const float* gcv = (const float*)&gc;
#pragma unroll
  for (int j = 0; j < 4; j++) {
    int ww = w0c + j;
    float s = 0.f;
#pragma unroll
    for (int dh = 0; dh < 3; dh++)
#pragma unroll
      for (int dw = 0; dw < 3; dw++)
        s += xs[hh + dh][ww + dw] * w0s[dh * 3 + dw];
    float v1 = gelu_f(s);
    vs[hh + 2][ww + 2] = v1;
    accv[j] = v1 * gav[j];
  }
  __syncthreads();

  float psum = 0.f;
#pragma unroll
  for (int j = 0; j < 4; j++) {
    int ww = w0c + j;
    float s = 0.f;
#pragma unroll
    for (int dh = 0; dh < 5; dh++)
#pragma unroll
      for (int dw = 0; dw < 5; dw++)
        s += vs[hh + dh][ww + dw] * w1s[dh * 5 + dw];
    float v2 = gelu_f(s);
    psum += v2;
    accv[j] += v2 * gbv[j];
  }
  for (int off = 32; off; off >>= 1) psum += __shfl_xor(psum, off);
  if ((t & 63) == 0) red[t >> 6] = psum;
  __syncthreads();
  float g = gelu_f((red[0] + red[1] + red[2] + red[3]) * (1.f / 1024.f));
  u16x4 o;
#pragma unroll
  for (int j = 0; j < 4; j++) o[j] = f2bf(accv[j] + g * gcv[j]);
  *(u16x4*)(accc + (size_t)bc * 1024 + t * 4) = o;
}

// ---------------- flash attention v3: no-max softmax, deferred denominator,
// batched tr64, XCD swizzle.
__global__ __launch_bounds__(512)
void flash_attn(const ushort_t* __restrict__ Q, const ushort_t* __restrict__ Kk,
                const ushort_t* __restrict__ V, ushort_t* __restrict__ Y, int kstride) {
  const int wg = blockIdx.x;
  const int swz = (wg & 7) * 64 + (wg >> 3);
  const int q0 = (swz & 3) * 128;
  const int h = (swz >> 2) & 7;
  const int b = swz >> 5;
  const int t = threadIdx.x, lane = t & 63, w = t >> 6;
  const int g = lane >> 4, l15 = lane & 15;
  __shared__ __attribute__((aligned(16))) ushort_t Ks[2][4096];
  __shared__ __attribute__((aligned(16))) ushort_t Vs[2][4096];
  __shared__ __attribute__((aligned(16))) ushort_t Ps[8][1024];

  const size_t qbase = (((size_t)b * NLAT) + q0 + w * 16 + l15) * CD + h * HD;
  bf16x8 aq[2];
#pragma unroll
  for (int kk = 0; kk < 2; kk++) {
    u16x8 u = *(const u16x8*)(Q + qbase + kk * 32 + g * 8);
    u16x8 o;
#pragma unroll
    for (int e = 0; e < 8; e++) o[e] = f2bf(bf2f(u[e]) * 0.125f);
    aq[kk] = *(bf16x8*)&o;
  }

  f32x4 accO[4] = {};
  float lsum[4] = {0.f, 0.f, 0.f, 0.f};
  const ushort_t* Kb = Kk + ((size_t)b * NCTX) * kstride + h * HD;
  const ushort_t* Vb = V  + ((size_t)b * NCTX) * CD + h * HD;
  const int krow = t >> 3;
  const int kseg = 8 * ((t & 7) ^ (krow & 7));
  const int vrow = (t >> 1) & 63;
  const int vcol = (t >> 7) * 16 + (t & 1) * 8;

  auto stage = [&](int buf, int kv) {
    const int k0 = kv * 64;
    gload16(Kb + (size_t)(k0 + krow) * kstride + kseg, &Ks[buf][t * 8]);
    gload16(Vb + (size_t)(k0 + vrow) * CD + vcol, &Vs[buf][t * 8]);
  };

  const unsigned vsbase0 = (unsigned)(size_t)(lptr3)&Vs[0][0];
  const unsigned vsbase1 = (unsigned)(size_t)(lptr3)&Vs[1][0];
  char* psb = (char*)&Ps[w][0];

  stage(0, 0);
  __syncthreads();
  int cur = 0;
  for (int kv = 0; kv < 16; kv++) {
    if (kv < 15) stage(cur ^ 1, kv + 1);

    const char* ksb = (const char*)&Ks[cur][0];
    f32x4 accS[4] = {};
#pragma unroll
    for (int kk = 0; kk < 2; kk++) {
#pragma unroll
      for (int n = 0; n < 4; n++) {
        int rr = n * 16 + l15;
        bf16x8 bk = *(const bf16x8*)(ksb + rr * 128 + ((kk * 64 + g * 16) ^ ((rr & 7) << 4)));
        accS[n] = __builtin_amdgcn_mfma_f32_16x16x32_bf16(aq[kk], bk, accS[n], 0, 0, 0);
      }
    }

#pragma unroll
    for (int n = 0; n < 4; n++)
#pragma unroll
      for (int r = 0; r < 4; r++) {
        float p = __expf(accS[n][r]);
        accS[n][r] = p;
        lsum[r] += p;
      }

#pragma unroll
    for (int n = 0; n < 4; n++)
#pragma unroll
      for (int r = 0; r < 4; r++) {
        int row = g * 4 + r;
        int cb = (n * 16 + l15) * 2;
        *(ushort_t*)(psb + row * 128 + (cb ^ ((row & 7) << 4))) = f2bf(accS[n][r]);
      }
    asm volatile("s_waitcnt lgkmcnt(0)" ::: "memory");
    __builtin_amdgcn_sched_barrier(0);
    bf16x8 ap0 = *(const bf16x8*)(psb + l15 * 128 + (((g * 16)) ^ ((l15 & 7) << 4)));
    bf16x8 ap1 = *(const bf16x8*)(psb + l15 * 128 + ((64 + g * 16) ^ ((l15 & 7) << 4)));

    const unsigned vsb = (cur ? vsbase1 : vsbase0) + g * 128;
    union PKU { u32x2 d2[2]; bf16x8 v; };
    PKU pk[8];
#pragma unroll
    for (int n = 0; n < 4; n++) {
      unsigned a = vsb + n * 2048;
      pk[n * 2].d2[0]     = tr64(a);
      pk[n * 2].d2[1]     = tr64(a + 128);
      pk[n * 2 + 1].d2[0] = tr64(a + 1024);
      pk[n * 2 + 1].d2[1] = tr64(a + 1152);
    }
    asm volatile("s_waitcnt lgkmcnt(0)" ::: "memory");
    __builtin_amdgcn_sched_barrier(0);
#pragma unroll
    for (int n = 0; n < 4; n++) {
      accO[n] = __builtin_amdgcn_mfma_f32_16x16x32_bf16(ap0, pk[n * 2].v, accO[n], 0, 0, 0);
      accO[n] = __builtin_amdgcn_mfma_f32_16x16x32_bf16(ap1, pk[n * 2 + 1].v, accO[n], 0, 0, 0);
    }
    __syncthreads();
    cur ^= 1;
  }

#pragma unroll
  for (int r = 0; r < 4; r++) {
    float s = lsum[r];
    s += __shfl_xor(s, 1); s += __shfl_xor(s, 2);
    s += __shfl_xor(s, 4); s += __shfl_xor(s, 8);
    lsum[r] = 1.f / s;
  }
#pragma unroll
  for (int n = 0; n < 4; n++) {
#pragma unroll
    for (int r = 0; r < 4; r++) {
      size_t row = q0 + w * 16 + g * 4 + r;
      size_t col = h * HD + n * 16 + l15;
      Y[(((size_t)b * NLAT) + row) * CD + col] = f2bf(accO[n][r] * lsum[r]);
    }
  }
}

// ---------------- host orchestration
extern "C" void kernel_launch(void* const* d_in, const int* in_sizes, int n_in,
                              void* d_out, int out_size, void* d_ws, size_t ws_size,
                              hipStream_t stream) {
  const float* latents  = (const float*)d_in[0];
  const float* context  = (const float*)d_in[1];
  const float* norm_l_w = (const float*)d_in[4];
  const float* norm_l_b = (const float*)d_in[5];
  const float* norm_c_w = (const float*)d_in[6];
  const float* norm_c_b = (const float*)d_in[7];
  const float* norm2_w  = (const float*)d_in[8];
  const float* norm2_b  = (const float*)d_in[9];
  const float* Wq    = (const float*)d_in[10];
  const float* Wk    = (const float*)d_in[11];
  const float* Wf    = (const float*)d_in[12];
  const float* bfv   = (const float*)d_in[13];
  const float* fk0   = (const float*)d_in[14];
  const float* fk1   = (const float*)d_in[15];
  const float* h_w   = (const float*)d_in[16];
  const float* h_b   = (const float*)d_in[17];
  const float* Wproj = (const float*)d_in[18];
  const float* bproj = (const float*)d_in[19];
  const float* fc1_w = (const float*)d_in[20];
  const float* fc1_b = (const float*)d_in[21];
  const float* fc2_w = (const float*)d_in[22];
  const float* fc2_b = (const float*)d_in[23];

  char* ws = (char*)d_ws;
  const size_t MB = 1024ull * 1024ull;
  ushort_t* WqT  = (ushort_t*)(ws + 0 * MB);
  ushort_t* WkT  = (ushort_t*)(ws + 1 * MB);
  ushort_t* WfT  = (ushort_t*)(ws + 1 * MB + 524288);
  ushort_t* hwT  = (ushort_t*)(ws + 3 * MB);
  ushort_t* WpT  = (ushort_t*)(ws + 4 * MB);
  ushort_t* fc1T = (ushort_t*)(ws + 5 * MB);
  ushort_t* fc2T = (ushort_t*)(ws + 7 * MB);
  float*    biaskf = (float*)(ws + 9 * MB);
  ushort_t* xl    = (ushort_t*)(ws + 10 * MB);
  ushort_t* xc    = (ushort_t*)(ws + 18 * MB);
  ushort_t* qb    = (ushort_t*)(ws + 34 * MB);
  ushort_t* kf    = (ushort_t*)(ws + 42 * MB);
  float*    gates = (float*)   (ws + 74 * MB);
  ushort_t* ftp   = (ushort_t*)(ws + 75 * MB);
  ushort_t* accc  = (ushort_t*)(ws + 91 * MB);
  ushort_t* acct  = (ushort_t*)(ws + 18 * MB);
  ushort_t* vb    = (ushort_t*)(ws + 75 * MB);
  ushort_t* yb    = (ushort_t*)(ws + 10 * MB);
  float*    lat1  = (float*)   (ws + 18 * MB);
  ushort_t* h2    = (ushort_t*)(ws + 34 * MB);
  ushort_t* a1    = (ushort_t*)(ws + 42 * MB);

  dim3 b256(256), b512(512);
  // 1. merged prep: weight transposes + bias_cat + both input LayerNorms
  prep_all<<<dim3(9489), b256, 0, stream>>>(Wq, Wk, Wf, h_w, Wproj, fc1_w, fc2_w, bfv,
                                            WqT, WkT, WfT, hwT, WpT, fc1T, fc2T, biaskf,
                                            latents, norm_l_w, norm_l_b, xl,
                                            context, norm_c_w, norm_c_b, xc);
  // 2. projections: q ; fused k|f ; gates
  gemm10<128,64, 0,0,0,1><<<dim3(64, 8),   b256, 0, stream>>>(xl, WqT, nullptr, nullptr, qb, 512, 512);
  gemm10<128,64, 0,1,0,1><<<dim3(128, 16), b256, 0, stream>>>(xc, WkT, biaskf, nullptr, kf, 1024, 512);
  gates_kernel<<<dim3(4096), b256, 0, stream>>>(xc, WfT, bfv, gates);
  // 3. focal modulation branch
  tr_bf16<<<dim3(16, 8, 16), b256, 0, stream>>>(kf + 512, ftp, 1024, 512, 1024, (size_t)1024*1024, (size_t)512*1024);
  focal_conv<<<dim3(8192), b256, 0, stream>>>(ftp, gates, fk0, fk1, accc);
  tr_bf16<<<dim3(8, 16, 16), b256, 0, stream>>>(accc, acct, 512, 1024, 1024, (size_t)512*1024, (size_t)1024*512);
  gemm10<128,64, 0,1,0,1><<<dim3(128, 8), b256, 0, stream>>>(acct, hwT, h_b, nullptr, vb, 512, 512);
  // 4. attention + proj (+ residual)
  flash_attn<<<dim3(512), b512, 0, stream>>>(qb, kf, vb, yb, 1024);
  gemm10<128,64, 0,1,1,0><<<dim3(64, 8), b256, 0, stream>>>(yb, WpT, bproj, latents, lat1, 512, 512);
  // 5. MLP (+ residual) -> d_out (f32)
  ln_kernel<<<dim3(2048), b256, 0, stream>>>(lat1, norm2_w, norm2_b, h2, 8192);
  gemm10<128,64, 1,1,0,1><<<dim3(64, 32), b256, 0, stream>>>(h2, fc1T, fc1_b, nullptr, a1, 2048, 512);
  gemm10<128,64, 0,1,1,0><<<dim3(64, 8),  b256, 0, stream>>>(a1, fc2T, fc2_b, lat1, d_out, 512, 2048);
  (void)in_sizes; (void)n_in; (void)out_size; (void)ws_size;
}